// Round 9
// baseline (203.324 us; speedup 1.0000x reference)
//
#include <hip/hip_runtime.h>
#include <hip/hip_bf16.h>

typedef __attribute__((ext_vector_type(8))) short bf16x8;
typedef __attribute__((ext_vector_type(4))) float f32x4;
typedef __attribute__((ext_vector_type(4))) unsigned short u16x4;
typedef unsigned short US;

__device__ __forceinline__ f32x4 mfma16(bf16x8 a, bf16x8 b, f32x4 c) {
  return __builtin_amdgcn_mfma_f32_16x16x32_bf16(a, b, c, 0, 0, 0);
}

__device__ __forceinline__ US f2bf(float f) {
  union { float f; unsigned u; } x; x.f = f;
  unsigned r = x.u + 0x7fffu + ((x.u >> 16) & 1u);
  return (US)(r >> 16);
}

// async global->LDS, 16B per lane; LDS dest = wave-uniform base + lane*16
__device__ __forceinline__ void gld16(const US* gp, US* lp) {
  __builtin_amdgcn_global_load_lds(
      (const __attribute__((address_space(1))) unsigned*)gp,
      (__attribute__((address_space(3))) unsigned*)lp, 16, 0, 0);
}

// RoPE column permutation: logical h (0..127) -> physical p; partner h+128 -> p+16.
__device__ __forceinline__ int permq(int h) {  // h in [0,128)
  return ((h >> 5) << 6) + (h & 15) + (((h >> 4) & 1) << 5);
}

// row remap fusing the time-concat: mode1: r=b*768+s -> b*1024+s ; mode2: r=b*256+s -> b*1024+768+s
__device__ __forceinline__ int map_row(int r, int mode) {
  if (mode == 1) { int b = r / 768; return b * 1024 + (r - b * 768); }
  if (mode == 2) { int b = r >> 8; return b * 1024 + 768 + (r & 255); }
  return r;
}

// ------- fused prep: casts + all 6 weight transpose-packs + sin/cos table -------
__global__ __launch_bounds__(256)
void k_prep(const float* __restrict__ x0, const float* __restrict__ x1,
            US* __restrict__ x0b, US* __restrict__ x1b,
            const float* __restrict__ wq0, const float* __restrict__ wkv0,
            const float* __restrict__ wq1, const float* __restrict__ wkv1,
            const float* __restrict__ wo0, const float* __restrict__ wo1,
            US* __restrict__ btq0, US* __restrict__ btkv0,
            US* __restrict__ btq1, US* __restrict__ btkv1,
            US* __restrict__ bto0, US* __restrict__ bto1,
            const int* __restrict__ pos, float2* __restrict__ sct) {
  const int bid = blockIdx.x;
  const int tid = threadIdx.x;
  if (bid >= 20992) {  // sin/cos table: 2048 blocks, 512K entries
    int idx = (bid - 20992) * 256 + tid;
    int bt = idx >> 7, j = idx & 127;
    float inv_ts = powf(10000.0f, -(float)j * (1.0f / 128.0f));
    float r = (float)pos[bt] * inv_ts;
    sct[idx] = make_float2(sinf(r), cosf(r));
    return;
  }
  if (bid < 7168) {  // bf16 casts
    const float* src; US* dst; int i;
    if (bid < 6144) { src = x0; dst = x0b; i = bid * 256 + tid; }
    else            { src = x1; dst = x1b; i = (bid - 6144) * 256 + tid; }
    f32x4 v = *reinterpret_cast<const f32x4*>(src + (size_t)i * 4);
    u16x4 o;
    o[0] = f2bf(v[0]); o[1] = f2bf(v[1]); o[2] = f2bf(v[2]); o[3] = f2bf(v[3]);
    *reinterpret_cast<u16x4*>(dst + (size_t)i * 4) = o;
    return;
  }
  __shared__ float tile[32][33];
  const float* src; US* dst; int R, C, CX, local; long sbs, dbs; bool pq = false;
  if (bid < 11264)      { local = bid - 7168;  src = wq0;  dst = btq0;  R = 2048; C = 256;  CX = 8;  sbs = 2048L * 256; dbs = 256L * 2048; pq = true; }
  else if (bid < 12288) { local = bid - 11264; src = wkv0; dst = btkv0; R = 2048; C = 256;  CX = 8;  sbs = 2048L * 256; dbs = 256L * 2048; }
  else if (bid < 14336) { local = bid - 12288; src = wq1;  dst = btq1;  R = 1024; C = 256;  CX = 8;  sbs = 1024L * 256; dbs = 256L * 1024; pq = true; }
  else if (bid < 14848) { local = bid - 14336; src = wkv1; dst = btkv1; R = 1024; C = 256;  CX = 8;  sbs = 1024L * 256; dbs = 256L * 1024; }
  else if (bid < 18944) { local = bid - 14848; src = wo0;  dst = bto0;  R = 2048; C = 2048; CX = 64; sbs = 0; dbs = 0; }
  else                  { local = bid - 18944; src = wo1;  dst = bto1;  R = 2048; C = 1024; CX = 32; sbs = 0; dbs = 0; }
  const int RY = R >> 5;
  const int cx = local % CX;
  const int rest = local / CX;
  const int ry = rest % RY;
  const int z = rest / RY;
  const int c0 = cx * 32, r0 = ry * 32;
  const int tx = tid & 31, ty = tid >> 5;
  src += (long)z * sbs;
  dst += (long)z * dbs;
#pragma unroll
  for (int i = 0; i < 4; ++i)
    tile[ty + 8 * i][tx] = src[(size_t)(r0 + ty + 8 * i) * C + c0 + tx];
  __syncthreads();
#pragma unroll
  for (int i = 0; i < 4; ++i) {
    int h = c0 + ty + 8 * i;
    int ph = pq ? ((h < 128) ? permq(h) : permq(h - 128) + 16) : h;
    dst[(size_t)ph * R + r0 + tx] = f2bf(tile[tx][ty + 8 * i]);
  }
}

// ------- merged QKV projection GEMM (both streams, one launch, XCD-swizzled) -------
__global__ __launch_bounds__(256, 2)
void k_gemm_qkv(const US* __restrict__ x0b, const US* __restrict__ x1b,
                const US* __restrict__ btq0, const US* __restrict__ btq1,
                US* __restrict__ q_bf, float* __restrict__ Ckv,
                const float2* __restrict__ sct) {
  const int bid = blockIdx.x;
  int id = (bid & 7) * 80 + (bid >> 3);   // bijective XCD swizzle (640 = 8*80)
  const US* A; const US* BT; int K, cmap, by, bx;
  if (id < 480) { A = x0b; BT = btq0; K = 2048; cmap = 1; by = id / 20; bx = id % 20; }
  else { id -= 480; A = x1b; BT = btq1; K = 1024; cmap = 2; by = id / 20; bx = id % 20; }

  __shared__ __align__(16) US lA[2][128 * 32];
  __shared__ __align__(16) US lB[2][128 * 32];
  const int tid = threadIdx.x;
  const int lane = tid & 63;
  const int wid = tid >> 6;
  const int wm = wid >> 1, wn = wid & 1;
  const int m0 = by * 128, n0 = bx * 128;
  const int g = lane >> 4, c = lane & 15;
  const int lrow = lane >> 2, lcol = (lane & 3) * 8;
  const size_t ga0 = (size_t)(m0 + wid * 16 + lrow) * K + lcol;
  const size_t ga1 = (size_t)(m0 + 64 + wid * 16 + lrow) * K + lcol;
  const size_t gb0 = (size_t)(n0 + wid * 16 + lrow) * K + lcol;
  const size_t gb1 = (size_t)(n0 + 64 + wid * 16 + lrow) * K + lcol;

  auto stage = [&](int bi, int k0) {
    gld16(A + ga0 + k0, &lA[bi][(wid * 16) * 32]);
    gld16(A + ga1 + k0, &lA[bi][(64 + wid * 16) * 32]);
    gld16(BT + gb0 + k0, &lB[bi][(wid * 16) * 32]);
    gld16(BT + gb1 + k0, &lB[bi][(64 + wid * 16) * 32]);
  };

  f32x4 acc[4][4];
#pragma unroll
  for (int i = 0; i < 4; ++i)
#pragma unroll
    for (int j = 0; j < 4; ++j) acc[i][j] = f32x4{0.f, 0.f, 0.f, 0.f};

  const int nt = K >> 5;
  stage(0, 0);
  __syncthreads();
  for (int t = 0; t < nt; ++t) {
    const int bi = t & 1;
    if (t + 1 < nt) stage(bi ^ 1, (t + 1) * 32);
    bf16x8 af[4], bfr[4];
#pragma unroll
    for (int i = 0; i < 4; ++i) {
      af[i] = *reinterpret_cast<const bf16x8*>(&lA[bi][(wm * 64 + i * 16 + c) * 32 + g * 8]);
      bfr[i] = *reinterpret_cast<const bf16x8*>(&lB[bi][(wn * 64 + i * 16 + c) * 32 + g * 8]);
    }
#pragma unroll
    for (int i = 0; i < 4; ++i)
#pragma unroll
      for (int j = 0; j < 4; ++j)
        acc[i][j] = mfma16(af[i], bfr[j], acc[i][j]);
    __syncthreads();  // drains vmcnt(0): prefetch landed; buf[bi] reads done
  }

  const int colb = n0 + wn * 64;
  if (colb < 2048) {
    // q path: RoPE + scale -> bf16 (permuted layout; pairs are (j0,j1),(j2,j3))
    const int n = colb >> 8;
    const int base64 = colb & 255;
    const int h0 = (base64 >> 6) * 32 + c;
    const float scale = 0.0625f;
#pragma unroll
    for (int i = 0; i < 4; ++i) {
#pragma unroll
      for (int r = 0; r < 4; ++r) {
        const int orow = map_row(m0 + wm * 64 + i * 16 + 4 * g + r, cmap);
        const float2 sc0 = sct[orow * 128 + h0];
        const float2 sc1 = sct[orow * 128 + h0 + 16];
        US* qp = q_bf + ((size_t)orow * 8 + n) * 256 + base64 + c;
        const float q1 = acc[i][0][r], q2 = acc[i][1][r];
        const float q3 = acc[i][2][r], q4 = acc[i][3][r];
        qp[0]  = f2bf(scale * (q1 * sc0.y - q2 * sc0.x));
        qp[16] = f2bf(scale * (q2 * sc0.y + q1 * sc0.x));
        qp[32] = f2bf(scale * (q3 * sc1.y - q4 * sc1.x));
        qp[48] = f2bf(scale * (q4 * sc1.y + q3 * sc1.x));
      }
    }
  } else {
    const int nb = colb - 2048 + c;
#pragma unroll
    for (int i = 0; i < 4; ++i) {
#pragma unroll
      for (int r = 0; r < 4; ++r) {
        const int orow = map_row(m0 + wm * 64 + i * 16 + 4 * g + r, cmap);
        float* cp = Ckv + (size_t)orow * 512 + nb;
#pragma unroll
        for (int j = 0; j < 4; ++j) cp[j * 16] = acc[i][j][r];
      }
    }
  }
}

// ------- compact output GEMM: 448 tiles (384 out0 + 64 out1), XCD-swizzled -------
__global__ __launch_bounds__(256, 2)
void k_gemm_out(const US* __restrict__ A, const US* __restrict__ BT0, const US* __restrict__ BT1,
                float* __restrict__ C0, float* __restrict__ C1) {
  const int bid = blockIdx.x;
  int id = (bid & 7) * 56 + (bid >> 3);   // bijective XCD swizzle (448 = 8*56)
  const US* BT; float* Cb; int amap, mt, ntile, Nst;
  if (id < 384) { amap = 1; mt = id / 16; ntile = id % 16; BT = BT0; Cb = C0; Nst = 2048; }
  else { id -= 384; amap = 2; mt = id / 8; ntile = id % 8; BT = BT1; Cb = C1; Nst = 1024; }
  const int m0 = mt * 128, n0 = ntile * 128;
  const int K = 2048;
  __shared__ __align__(16) US lA[2][128 * 32];
  __shared__ __align__(16) US lB[2][128 * 32];
  const int tid = threadIdx.x;
  const int lane = tid & 63;
  const int wid = tid >> 6;
  const int wm = wid >> 1, wn = wid & 1;
  const int g = lane >> 4, c = lane & 15;
  const int lrow = lane >> 2, lcol = (lane & 3) * 8;
  const size_t ga0 = (size_t)map_row(m0 + wid * 16 + lrow, amap) * K + lcol;
  const size_t ga1 = (size_t)map_row(m0 + 64 + wid * 16 + lrow, amap) * K + lcol;
  const size_t gb0 = (size_t)(n0 + wid * 16 + lrow) * K + lcol;
  const size_t gb1 = (size_t)(n0 + 64 + wid * 16 + lrow) * K + lcol;

  auto stage = [&](int bi, int k0) {
    gld16(A + ga0 + k0, &lA[bi][(wid * 16) * 32]);
    gld16(A + ga1 + k0, &lA[bi][(64 + wid * 16) * 32]);
    gld16(BT + gb0 + k0, &lB[bi][(wid * 16) * 32]);
    gld16(BT + gb1 + k0, &lB[bi][(64 + wid * 16) * 32]);
  };

  f32x4 acc[4][4];
#pragma unroll
  for (int i = 0; i < 4; ++i)
#pragma unroll
    for (int j = 0; j < 4; ++j) acc[i][j] = f32x4{0.f, 0.f, 0.f, 0.f};

  const int nt = K >> 5;
  stage(0, 0);
  __syncthreads();
  for (int t = 0; t < nt; ++t) {
    const int bi = t & 1;
    if (t + 1 < nt) stage(bi ^ 1, (t + 1) * 32);
    bf16x8 af[4], bfr[4];
#pragma unroll
    for (int i = 0; i < 4; ++i) {
      af[i] = *reinterpret_cast<const bf16x8*>(&lA[bi][(wm * 64 + i * 16 + c) * 32 + g * 8]);
      bfr[i] = *reinterpret_cast<const bf16x8*>(&lB[bi][(wn * 64 + i * 16 + c) * 32 + g * 8]);
    }
#pragma unroll
    for (int i = 0; i < 4; ++i)
#pragma unroll
      for (int j = 0; j < 4; ++j)
        acc[i][j] = mfma16(af[i], bfr[j], acc[i][j]);
    __syncthreads();
  }

  const int col = n0 + wn * 64 + c;
#pragma unroll
  for (int i = 0; i < 4; ++i) {
#pragma unroll
    for (int r = 0; r < 4; ++r) {
      const int orow = m0 + wm * 64 + i * 16 + 4 * g + r;  // compact per-segment row
      float* cp = Cb + (size_t)orow * Nst + col;
#pragma unroll
      for (int j = 0; j < 4; ++j) cp[j * 16] = acc[i][j][r];
    }
  }
}

// ------- merged post-KV: V transpose (+v_out) and k-RoPE (+k_out) in one launch -------
__global__ __launch_bounds__(256)
void k_postkv(const float* __restrict__ kv_raw, const float2* __restrict__ sct,
              US* __restrict__ k_bf, float* __restrict__ k_out,
              float* __restrict__ v_out, US* __restrict__ vt) {
  const int bid = blockIdx.x;
  const int tid = threadIdx.x;
  if (bid >= 1024) {  // k-RoPE: 2048 blocks, 2 bt-rows each
    const int bt = (bid - 1024) * 2 + (tid >> 7);
    const int j = tid & 127;
    const size_t ko = (size_t)bt * 512;
    const float x1 = kv_raw[ko + j], x2 = kv_raw[ko + j + 128];
    const float2 sc = sct[bt * 128 + j];
    const float o1 = x1 * sc.y - x2 * sc.x, o2 = x2 * sc.y + x1 * sc.x;
    const size_t kd = (size_t)bt * 256;
    const int p = permq(j);
    k_bf[kd + p] = f2bf(o1);
    k_bf[kd + p + 16] = f2bf(o2);
    k_out[kd + j] = o1;
    k_out[kd + j + 128] = o2;
    return;
  }
  __shared__ float tile[32][33];
  const int t0 = (bid & 31) * 32, h0 = ((bid >> 5) & 7) * 32, b = bid >> 8;
  const int tx = tid & 31, ty = tid >> 5;
#pragma unroll
  for (int i = 0; i < 4; ++i) {
    int t = t0 + ty + 8 * i;
    float v = kv_raw[(size_t)(b * 1024 + t) * 512 + 256 + h0 + tx];
    tile[ty + 8 * i][tx] = v;
    v_out[(size_t)(b * 1024 + t) * 256 + h0 + tx] = v;
  }
  __syncthreads();
#pragma unroll
  for (int i = 0; i < 4; ++i) {
    int h = h0 + ty + 8 * i;
    vt[(size_t)(b * 256 + h) * 1024 + t0 + tx] = f2bf(tile[tx][ty + 8 * i]);
  }
}

// ------- flash attention: 512 blocks x 128 threads (2 waves = 2 heads) -------
// In-block qt-PAIRING: block processes qt=63-pr then qt=pr sequentially ->
// exactly 33-34 chunks per block, uniform by construction (no dispatch-mapping
// assumptions). K+V LDS double-buffered, XOR-swizzled; defer-max; paf butterfly.
__global__ __launch_bounds__(128, 2)
void k_attn(const US* __restrict__ qb, const US* __restrict__ kb,
            const US* __restrict__ vt, US* __restrict__ enc) {
  __shared__ __align__(16) US lK[2][32 * 256];   // 16KB x2
  __shared__ __align__(16) US lV[2][256 * 32];   // 16KB x2
  const int id = blockIdx.x;
  const int pr = id >> 4;          // qt-pair index 0..31
  const int hg = (id >> 2) & 3;    // 2-head group
  const int b = id & 3;
  const int tid = threadIdx.x;
  const int wid = tid >> 6;
  const int lane = tid & 63;
  const int g = lane >> 4, c = lane & 15;
  const int n = hg * 2 + wid;

  const US* kbB = kb + (size_t)b * 262144;
  const US* vtB = vt + (size_t)b * 262144;

  // stage chunk [c0..c0+31]: K granule (r,s) holds global col-granule s^(r&7);
  // V granule (r,s) holds global col-granule s^((r>>1)&3). 2 waves cover the tiles.
  auto stage = [&](int bi, int c0) {
#pragma unroll
    for (int j = 0; j < 8; ++j) {
      const int rk = wid * 16 + j * 2 + (lane >> 5);
      const int sk = lane & 31;
      gld16(kbB + (size_t)(c0 + rk) * 256 + (sk ^ (rk & 7)) * 8,
            &lK[bi][(wid * 16 + j * 2) * 256]);
      const int rv = wid * 128 + j * 16 + (lane >> 2);
      const int sv = lane & 3;
      gld16(vtB + (size_t)rv * 1024 + c0 + (sv ^ ((rv >> 1) & 3)) * 8,
            &lV[bi][(wid * 128 + j * 16) * 32]);
    }
  };

#pragma unroll 1
  for (int half = 0; half < 2; ++half) {
    const int qt = (half == 0) ? 63 - pr : pr;
    const int qbase = qt * 16;

    bf16x8 qf[8];
    {
      const US* qp = qb + ((size_t)((b * 1024 + qbase + c) * 8 + n)) * 256 + 8 * g;
#pragma unroll
      for (int ch = 0; ch < 8; ++ch)
        qf[ch] = *reinterpret_cast<const bf16x8*>(qp + ch * 32);
    }

    f32x4 acc[16];
#pragma unroll
    for (int i = 0; i < 16; ++i) acc[i] = f32x4{0.f, 0.f, 0.f, 0.f};
    float m_run = -3.0e38f, l_run = 0.f;

    const int nC = qbase / 32 + 1;
    stage(0, 0);
    __syncthreads();

    for (int i = 0; i < nC; ++i) {
      const int c0 = 32 * i;
      const int bi = i & 1;
      if (i + 1 < nC) stage(bi ^ 1, c0 + 32);

      const bool hb = (c0 + 16 <= qbase);
      f32x4 sA = {0.f, 0.f, 0.f, 0.f}, sB = {0.f, 0.f, 0.f, 0.f};
      __builtin_amdgcn_s_setprio(1);
#pragma unroll
      for (int ch = 0; ch < 8; ++ch) {
        const int slot = (((ch * 4 + g) ^ (c & 7)) * 8);
        sA = mfma16(*reinterpret_cast<const bf16x8*>(&lK[bi][c * 256 + slot]), qf[ch], sA);
      }
      if (hb) {
#pragma unroll
        for (int ch = 0; ch < 8; ++ch) {
          const int slot = (((ch * 4 + g) ^ (c & 7)) * 8);  // (c+16)&7 == c&7
          sB = mfma16(*reinterpret_cast<const bf16x8*>(&lK[bi][(c + 16) * 256 + slot]), qf[ch], sB);
        }
      }
      __builtin_amdgcn_s_setprio(0);
      if (c0 == qbase) {
#pragma unroll
        for (int r = 0; r < 4; ++r)
          if (4 * g + r > c) sA[r] = -3.0e38f;
      }
      if (hb && (c0 + 16 == qbase)) {
#pragma unroll
        for (int r = 0; r < 4; ++r)
          if (4 * g + r > c) sB[r] = -3.0e38f;
      }
      float tm = fmaxf(fmaxf(sA[0], sA[1]), fmaxf(sA[2], sA[3]));
      if (hb) tm = fmaxf(tm, fmaxf(fmaxf(sB[0], sB[1]), fmaxf(sB[2], sB[3])));
      tm = fmaxf(tm, __shfl_xor(tm, 16));
      tm = fmaxf(tm, __shfl_xor(tm, 32));
      // defer-max: only rescale when the running max actually grows past THR
      if (!__all(tm - m_run <= 8.0f)) {
        const float m_new = fmaxf(m_run, tm);
        const float alpha = __expf(m_run - m_new);
        float aacc[4];
#pragma unroll
        for (int r = 0; r < 4; ++r) aacc[r] = __shfl(alpha, 4 * g + r);
#pragma unroll
        for (int ht = 0; ht < 16; ++ht) {
          acc[ht][0] *= aacc[0]; acc[ht][1] *= aacc[1];
          acc[ht][2] *= aacc[2]; acc[ht][3] *= aacc[3];
        }
        l_run *= alpha;
        m_run = m_new;
      }
      float pA[4], pB[4];
      float ls = 0.f;
#pragma unroll
      for (int r = 0; r < 4; ++r) { pA[r] = __expf(sA[r] - m_run); ls += pA[r]; }
#pragma unroll
      for (int r = 0; r < 4; ++r) { pB[r] = hb ? __expf(sB[r] - m_run) : 0.f; ls += pB[r]; }
      ls += __shfl_xor(ls, 16);
      ls += __shfl_xor(ls, 32);
      l_run += ls;

      // --- paf butterfly: pack P to bf16 pairs, then 2-stage 4-lane-group transpose ---
      unsigned w0, w1, w2, w3;
      asm("v_cvt_pk_bf16_f32 %0, %1, %2" : "=v"(w0) : "v"(pA[0]), "v"(pA[1]));
      asm("v_cvt_pk_bf16_f32 %0, %1, %2" : "=v"(w1) : "v"(pA[2]), "v"(pA[3]));
      asm("v_cvt_pk_bf16_f32 %0, %1, %2" : "=v"(w2) : "v"(pB[0]), "v"(pB[1]));
      asm("v_cvt_pk_bf16_f32 %0, %1, %2" : "=v"(w3) : "v"(pB[2]), "v"(pB[3]));
      const bool bb1 = ((g >> 1) & 1) != 0, bb0 = (g & 1) != 0;
      unsigned ownA = bb1 ? w2 : w0, ownB = bb1 ? w3 : w1;
      unsigned sndA = bb1 ? w0 : w2, sndB = bb1 ? w1 : w3;
      unsigned rcvA = (unsigned)__shfl_xor((int)sndA, 32);
      unsigned rcvB = (unsigned)__shfl_xor((int)sndB, 32);
      unsigned kA = (bb0 == bb1) ? ownA : rcvA, kB = (bb0 == bb1) ? ownB : rcvB;
      unsigned s2A = (bb0 == bb1) ? rcvA : ownA, s2B = (bb0 == bb1) ? rcvB : ownB;
      unsigned gA = (unsigned)__shfl_xor((int)s2A, 16);
      unsigned gB = (unsigned)__shfl_xor((int)s2B, 16);
      union { unsigned u[4]; bf16x8 v; } pu;
      pu.u[0] = bb0 ? gA : kA; pu.u[1] = bb0 ? gB : kB;
      pu.u[2] = bb0 ? kA : gA; pu.u[3] = bb0 ? kB : gB;
      const bf16x8 paf = pu.v;

      __builtin_amdgcn_s_setprio(1);
#pragma unroll
      for (int ht = 0; ht < 16; ++ht) {
        const int h = ht * 16 + c;
        const int slot = (g ^ ((c >> 1) & 3)) * 8;
        bf16x8 vf = *reinterpret_cast<const bf16x8*>(&lV[bi][h * 32 + slot]);
        acc[ht] = mfma16(paf, vf, acc[ht]);
      }
      __builtin_amdgcn_s_setprio(0);
      __syncthreads();  // buf[bi] reads done; staging of buf[bi^1] drained
    }

    const float inv = 1.0f / l_run;
    float ia[4];
#pragma unroll
    for (int r = 0; r < 4; ++r) ia[r] = __shfl(inv, 4 * g + r);
#pragma unroll
    for (int ht = 0; ht < 16; ++ht) {
#pragma unroll
      for (int r = 0; r < 4; ++r) {
        size_t o = ((size_t)((b * 1024 + qbase + 4 * g + r) * 8 + n)) * 256 + ht * 16 + c;
        enc[o] = f2bf(acc[ht][r] * ia[r]);
      }
    }
  }
}

extern "C" void kernel_launch(void* const* d_in, const int* in_sizes, int n_in,
                              void* d_out, int out_size, void* d_ws, size_t ws_size,
                              hipStream_t stream) {
  const float* x0 = (const float*)d_in[0];
  const float* x1 = (const float*)d_in[1];
  const float* wq0 = (const float*)d_in[2];
  const float* wkv0 = (const float*)d_in[3];
  const float* wo0 = (const float*)d_in[4];
  const float* wq1 = (const float*)d_in[5];
  const float* wkv1 = (const float*)d_in[6];
  const float* wo1 = (const float*)d_in[7];
  const int* pos = (const int*)d_in[8];
  float* out = (float*)d_out;

  float* out0 = out;                    // 4*768*2048
  float* out1 = out + 6291456;          // 4*256*1024
  float* k_out = out + 7340032;         // 4*1024*256
  float* v_out = out + 8388608;         // 4*1024*256

  char* ws = (char*)d_ws;
  size_t off = 0;
  auto alloc = [&](size_t bytes) {
    char* p = ws + off;
    off += (bytes + 255) & ~(size_t)255;
    return p;
  };
  US* x0b   = (US*)alloc(6291456ull * 2);
  US* x1b   = (US*)alloc(1048576ull * 2);
  US* btq0  = (US*)alloc(2048ull * 2048 * 2);   // btq0+btkv0 contiguous: [2560][2048]
  US* btkv0 = (US*)alloc(512ull * 2048 * 2);
  US* btq1  = (US*)alloc(2048ull * 1024 * 2);   // btq1+btkv1 contiguous: [2560][1024]
  US* btkv1 = (US*)alloc(512ull * 1024 * 2);
  US* bto0  = (US*)alloc(2048ull * 2048 * 2);
  US* bto1  = (US*)alloc(1024ull * 2048 * 2);
  float* kv_raw = (float*)alloc(2097152ull * 4);
  US* q_bf = (US*)alloc(8388608ull * 2);
  US* k_bf = (US*)alloc(1048576ull * 2);
  US* vt   = (US*)alloc(1048576ull * 2 + 256);
  US* enc  = (US*)alloc(8388608ull * 2);
  float2* sct = (float2*)alloc(524288ull * 8);
  (void)btkv0; (void)btkv1;

  // phase 1: fused casts + weight packs + sin/cos table
  k_prep<<<23040, 256, 0, stream>>>(x0, x1, x0b, x1b, wq0, wkv0, wq1, wkv1, wo0, wo1,
                                    btq0, btkv0, btq1, btkv1, bto0, bto1, pos, sct);

  // phase 2: merged QKV projection GEMMs (both streams, RoPE-q fused epilogue)
  k_gemm_qkv<<<640, 256, 0, stream>>>(x0b, x1b, btq0, btq1, q_bf, kv_raw, sct);

  // phase 3: merged k-RoPE + V transpose (emit k, v fp32 outputs)
  k_postkv<<<3072, 256, 0, stream>>>(kv_raw, sct, k_bf, k_out, v_out, vt);

  // phase 4: causal flash attention (in-block qt-pairing, uniform 33-34 chunks)
  k_attn<<<512, 128, 0, stream>>>(q_bf, k_bf, vt, enc);

  // phase 5: compact fused output GEMM (448 tiles, no holes)
  k_gemm_out<<<448, 256, 0, stream>>>(enc, bto0, bto1, out0, out1);
}

// Round 10
// 190.484 us; speedup vs baseline: 1.0674x; 1.0674x over previous
//
#include <hip/hip_runtime.h>
#include <hip/hip_bf16.h>

typedef __attribute__((ext_vector_type(8))) short bf16x8;
typedef __attribute__((ext_vector_type(4))) float f32x4;
typedef __attribute__((ext_vector_type(4))) unsigned short u16x4;
typedef unsigned short US;

__device__ __forceinline__ f32x4 mfma16(bf16x8 a, bf16x8 b, f32x4 c) {
  return __builtin_amdgcn_mfma_f32_16x16x32_bf16(a, b, c, 0, 0, 0);
}

__device__ __forceinline__ US f2bf(float f) {
  union { float f; unsigned u; } x; x.f = f;
  unsigned r = x.u + 0x7fffu + ((x.u >> 16) & 1u);
  return (US)(r >> 16);
}

// async global->LDS, 16B per lane; LDS dest = wave-uniform base + lane*16
__device__ __forceinline__ void gld16(const US* gp, US* lp) {
  __builtin_amdgcn_global_load_lds(
      (const __attribute__((address_space(1))) unsigned*)gp,
      (__attribute__((address_space(3))) unsigned*)lp, 16, 0, 0);
}

// RoPE column permutation: logical h (0..127) -> physical p; partner h+128 -> p+16.
__device__ __forceinline__ int permq(int h) {  // h in [0,128)
  return ((h >> 5) << 6) + (h & 15) + (((h >> 4) & 1) << 5);
}

// row remap fusing the time-concat: mode1: r=b*768+s -> b*1024+s ; mode2: r=b*256+s -> b*1024+768+s
__device__ __forceinline__ int map_row(int r, int mode) {
  if (mode == 1) { int b = r / 768; return b * 1024 + (r - b * 768); }
  if (mode == 2) { int b = r >> 8; return b * 1024 + 768 + (r & 255); }
  return r;
}

// ------- fused prep: casts + qkv weight transpose-packs + sin/cos table -------
// (wo0/wo1 packs moved into the k_attn launch to overlap with attention)
__global__ __launch_bounds__(256)
void k_prep(const float* __restrict__ x0, const float* __restrict__ x1,
            US* __restrict__ x0b, US* __restrict__ x1b,
            const float* __restrict__ wq0, const float* __restrict__ wkv0,
            const float* __restrict__ wq1, const float* __restrict__ wkv1,
            US* __restrict__ btq0, US* __restrict__ btkv0,
            US* __restrict__ btq1, US* __restrict__ btkv1,
            const int* __restrict__ pos, float2* __restrict__ sct) {
  const int bid = blockIdx.x;
  const int tid = threadIdx.x;
  if (bid >= 14848) {  // sin/cos table: 2048 blocks, 512K entries
    int idx = (bid - 14848) * 256 + tid;
    int bt = idx >> 7, j = idx & 127;
    float inv_ts = powf(10000.0f, -(float)j * (1.0f / 128.0f));
    float r = (float)pos[bt] * inv_ts;
    sct[idx] = make_float2(sinf(r), cosf(r));
    return;
  }
  if (bid < 7168) {  // bf16 casts
    const float* src; US* dst; int i;
    if (bid < 6144) { src = x0; dst = x0b; i = bid * 256 + tid; }
    else            { src = x1; dst = x1b; i = (bid - 6144) * 256 + tid; }
    f32x4 v = *reinterpret_cast<const f32x4*>(src + (size_t)i * 4);
    u16x4 o;
    o[0] = f2bf(v[0]); o[1] = f2bf(v[1]); o[2] = f2bf(v[2]); o[3] = f2bf(v[3]);
    *reinterpret_cast<u16x4*>(dst + (size_t)i * 4) = o;
    return;
  }
  __shared__ float tile[32][33];
  const float* src; US* dst; int R, C, CX, local; long sbs, dbs; bool pq = false;
  if (bid < 11264)      { local = bid - 7168;  src = wq0;  dst = btq0;  R = 2048; C = 256; CX = 8; sbs = 2048L * 256; dbs = 256L * 2048; pq = true; }
  else if (bid < 12288) { local = bid - 11264; src = wkv0; dst = btkv0; R = 2048; C = 256; CX = 8; sbs = 2048L * 256; dbs = 256L * 2048; }
  else if (bid < 14336) { local = bid - 12288; src = wq1;  dst = btq1;  R = 1024; C = 256; CX = 8; sbs = 1024L * 256; dbs = 256L * 1024; pq = true; }
  else                  { local = bid - 14336; src = wkv1; dst = btkv1; R = 1024; C = 256; CX = 8; sbs = 1024L * 256; dbs = 256L * 1024; }
  const int RY = R >> 5;
  const int cx = local % CX;
  const int rest = local / CX;
  const int ry = rest % RY;
  const int z = rest / RY;
  const int c0 = cx * 32, r0 = ry * 32;
  const int tx = tid & 31, ty = tid >> 5;
  src += (long)z * sbs;
  dst += (long)z * dbs;
#pragma unroll
  for (int i = 0; i < 4; ++i)
    tile[ty + 8 * i][tx] = src[(size_t)(r0 + ty + 8 * i) * C + c0 + tx];
  __syncthreads();
#pragma unroll
  for (int i = 0; i < 4; ++i) {
    int h = c0 + ty + 8 * i;
    int ph = pq ? ((h < 128) ? permq(h) : permq(h - 128) + 16) : h;
    dst[(size_t)ph * R + r0 + tx] = f2bf(tile[tx][ty + 8 * i]);
  }
}

// ------- merged QKV projection GEMM (both streams, one launch, XCD-swizzled) -------
__global__ __launch_bounds__(256, 2)
void k_gemm_qkv(const US* __restrict__ x0b, const US* __restrict__ x1b,
                const US* __restrict__ btq0, const US* __restrict__ btq1,
                US* __restrict__ q_bf, float* __restrict__ Ckv,
                const float2* __restrict__ sct) {
  const int bid = blockIdx.x;
  int id = (bid & 7) * 80 + (bid >> 3);   // bijective XCD swizzle (640 = 8*80)
  const US* A; const US* BT; int K, cmap, by, bx;
  if (id < 480) { A = x0b; BT = btq0; K = 2048; cmap = 1; by = id / 20; bx = id % 20; }
  else { id -= 480; A = x1b; BT = btq1; K = 1024; cmap = 2; by = id / 20; bx = id % 20; }

  __shared__ __align__(16) US lA[2][128 * 32];
  __shared__ __align__(16) US lB[2][128 * 32];
  const int tid = threadIdx.x;
  const int lane = tid & 63;
  const int wid = tid >> 6;
  const int wm = wid >> 1, wn = wid & 1;
  const int m0 = by * 128, n0 = bx * 128;
  const int g = lane >> 4, c = lane & 15;
  const int lrow = lane >> 2, lcol = (lane & 3) * 8;
  const size_t ga0 = (size_t)(m0 + wid * 16 + lrow) * K + lcol;
  const size_t ga1 = (size_t)(m0 + 64 + wid * 16 + lrow) * K + lcol;
  const size_t gb0 = (size_t)(n0 + wid * 16 + lrow) * K + lcol;
  const size_t gb1 = (size_t)(n0 + 64 + wid * 16 + lrow) * K + lcol;

  auto stage = [&](int bi, int k0) {
    gld16(A + ga0 + k0, &lA[bi][(wid * 16) * 32]);
    gld16(A + ga1 + k0, &lA[bi][(64 + wid * 16) * 32]);
    gld16(BT + gb0 + k0, &lB[bi][(wid * 16) * 32]);
    gld16(BT + gb1 + k0, &lB[bi][(64 + wid * 16) * 32]);
  };

  f32x4 acc[4][4];
#pragma unroll
  for (int i = 0; i < 4; ++i)
#pragma unroll
    for (int j = 0; j < 4; ++j) acc[i][j] = f32x4{0.f, 0.f, 0.f, 0.f};

  const int nt = K >> 5;
  stage(0, 0);
  __syncthreads();
  for (int t = 0; t < nt; ++t) {
    const int bi = t & 1;
    if (t + 1 < nt) stage(bi ^ 1, (t + 1) * 32);
    bf16x8 af[4], bfr[4];
#pragma unroll
    for (int i = 0; i < 4; ++i) {
      af[i] = *reinterpret_cast<const bf16x8*>(&lA[bi][(wm * 64 + i * 16 + c) * 32 + g * 8]);
      bfr[i] = *reinterpret_cast<const bf16x8*>(&lB[bi][(wn * 64 + i * 16 + c) * 32 + g * 8]);
    }
#pragma unroll
    for (int i = 0; i < 4; ++i)
#pragma unroll
      for (int j = 0; j < 4; ++j)
        acc[i][j] = mfma16(af[i], bfr[j], acc[i][j]);
    __syncthreads();  // drains vmcnt(0): prefetch landed; buf[bi] reads done
  }

  const int colb = n0 + wn * 64;
  if (colb < 2048) {
    // q path: RoPE + scale -> bf16 (permuted layout; pairs are (j0,j1),(j2,j3))
    const int n = colb >> 8;
    const int base64 = colb & 255;
    const int h0 = (base64 >> 6) * 32 + c;
    const float scale = 0.0625f;
#pragma unroll
    for (int i = 0; i < 4; ++i) {
#pragma unroll
      for (int r = 0; r < 4; ++r) {
        const int orow = map_row(m0 + wm * 64 + i * 16 + 4 * g + r, cmap);
        const float2 sc0 = sct[orow * 128 + h0];
        const float2 sc1 = sct[orow * 128 + h0 + 16];
        US* qp = q_bf + ((size_t)orow * 8 + n) * 256 + base64 + c;
        const float q1 = acc[i][0][r], q2 = acc[i][1][r];
        const float q3 = acc[i][2][r], q4 = acc[i][3][r];
        qp[0]  = f2bf(scale * (q1 * sc0.y - q2 * sc0.x));
        qp[16] = f2bf(scale * (q2 * sc0.y + q1 * sc0.x));
        qp[32] = f2bf(scale * (q3 * sc1.y - q4 * sc1.x));
        qp[48] = f2bf(scale * (q4 * sc1.y + q3 * sc1.x));
      }
    }
  } else {
    const int nb = colb - 2048 + c;
#pragma unroll
    for (int i = 0; i < 4; ++i) {
#pragma unroll
      for (int r = 0; r < 4; ++r) {
        const int orow = map_row(m0 + wm * 64 + i * 16 + 4 * g + r, cmap);
        float* cp = Ckv + (size_t)orow * 512 + nb;
#pragma unroll
        for (int j = 0; j < 4; ++j) cp[j * 16] = acc[i][j][r];
      }
    }
  }
}

// ------- compact output GEMM: 448 tiles (384 out0 + 64 out1), XCD-swizzled -------
__global__ __launch_bounds__(256, 2)
void k_gemm_out(const US* __restrict__ A, const US* __restrict__ BT0, const US* __restrict__ BT1,
                float* __restrict__ C0, float* __restrict__ C1) {
  const int bid = blockIdx.x;
  int id = (bid & 7) * 56 + (bid >> 3);   // bijective XCD swizzle (448 = 8*56)
  const US* BT; float* Cb; int amap, mt, ntile, Nst;
  if (id < 384) { amap = 1; mt = id / 16; ntile = id % 16; BT = BT0; Cb = C0; Nst = 2048; }
  else { id -= 384; amap = 2; mt = id / 8; ntile = id % 8; BT = BT1; Cb = C1; Nst = 1024; }
  const int m0 = mt * 128, n0 = ntile * 128;
  const int K = 2048;
  __shared__ __align__(16) US lA[2][128 * 32];
  __shared__ __align__(16) US lB[2][128 * 32];
  const int tid = threadIdx.x;
  const int lane = tid & 63;
  const int wid = tid >> 6;
  const int wm = wid >> 1, wn = wid & 1;
  const int g = lane >> 4, c = lane & 15;
  const int lrow = lane >> 2, lcol = (lane & 3) * 8;
  const size_t ga0 = (size_t)map_row(m0 + wid * 16 + lrow, amap) * K + lcol;
  const size_t ga1 = (size_t)map_row(m0 + 64 + wid * 16 + lrow, amap) * K + lcol;
  const size_t gb0 = (size_t)(n0 + wid * 16 + lrow) * K + lcol;
  const size_t gb1 = (size_t)(n0 + 64 + wid * 16 + lrow) * K + lcol;

  auto stage = [&](int bi, int k0) {
    gld16(A + ga0 + k0, &lA[bi][(wid * 16) * 32]);
    gld16(A + ga1 + k0, &lA[bi][(64 + wid * 16) * 32]);
    gld16(BT + gb0 + k0, &lB[bi][(wid * 16) * 32]);
    gld16(BT + gb1 + k0, &lB[bi][(64 + wid * 16) * 32]);
  };

  f32x4 acc[4][4];
#pragma unroll
  for (int i = 0; i < 4; ++i)
#pragma unroll
    for (int j = 0; j < 4; ++j) acc[i][j] = f32x4{0.f, 0.f, 0.f, 0.f};

  const int nt = K >> 5;
  stage(0, 0);
  __syncthreads();
  for (int t = 0; t < nt; ++t) {
    const int bi = t & 1;
    if (t + 1 < nt) stage(bi ^ 1, (t + 1) * 32);
    bf16x8 af[4], bfr[4];
#pragma unroll
    for (int i = 0; i < 4; ++i) {
      af[i] = *reinterpret_cast<const bf16x8*>(&lA[bi][(wm * 64 + i * 16 + c) * 32 + g * 8]);
      bfr[i] = *reinterpret_cast<const bf16x8*>(&lB[bi][(wn * 64 + i * 16 + c) * 32 + g * 8]);
    }
#pragma unroll
    for (int i = 0; i < 4; ++i)
#pragma unroll
      for (int j = 0; j < 4; ++j)
        acc[i][j] = mfma16(af[i], bfr[j], acc[i][j]);
    __syncthreads();
  }

  const int col = n0 + wn * 64 + c;
#pragma unroll
  for (int i = 0; i < 4; ++i) {
#pragma unroll
    for (int r = 0; r < 4; ++r) {
      const int orow = m0 + wm * 64 + i * 16 + 4 * g + r;  // compact per-segment row
      float* cp = Cb + (size_t)orow * Nst + col;
#pragma unroll
      for (int j = 0; j < 4; ++j) cp[j * 16] = acc[i][j][r];
    }
  }
}

// ------- merged post-KV: V transpose (+v_out) and k-RoPE (+k_out) in one launch -------
__global__ __launch_bounds__(256)
void k_postkv(const float* __restrict__ kv_raw, const float2* __restrict__ sct,
              US* __restrict__ k_bf, float* __restrict__ k_out,
              float* __restrict__ v_out, US* __restrict__ vt) {
  const int bid = blockIdx.x;
  const int tid = threadIdx.x;
  if (bid >= 1024) {  // k-RoPE: 2048 blocks, 2 bt-rows each
    const int bt = (bid - 1024) * 2 + (tid >> 7);
    const int j = tid & 127;
    const size_t ko = (size_t)bt * 512;
    const float x1 = kv_raw[ko + j], x2 = kv_raw[ko + j + 128];
    const float2 sc = sct[bt * 128 + j];
    const float o1 = x1 * sc.y - x2 * sc.x, o2 = x2 * sc.y + x1 * sc.x;
    const size_t kd = (size_t)bt * 256;
    const int p = permq(j);
    k_bf[kd + p] = f2bf(o1);
    k_bf[kd + p + 16] = f2bf(o2);
    k_out[kd + j] = o1;
    k_out[kd + j + 128] = o2;
    return;
  }
  __shared__ float tile[32][33];
  const int t0 = (bid & 31) * 32, h0 = ((bid >> 5) & 7) * 32, b = bid >> 8;
  const int tx = tid & 31, ty = tid >> 5;
#pragma unroll
  for (int i = 0; i < 4; ++i) {
    int t = t0 + ty + 8 * i;
    float v = kv_raw[(size_t)(b * 1024 + t) * 512 + 256 + h0 + tx];
    tile[ty + 8 * i][tx] = v;
    v_out[(size_t)(b * 1024 + t) * 256 + h0 + tx] = v;
  }
  __syncthreads();
#pragma unroll
  for (int i = 0; i < 4; ++i) {
    int h = h0 + ty + 8 * i;
    vt[(size_t)(b * 256 + h) * 1024 + t0 + tx] = f2bf(tile[tx][ty + 8 * i]);
  }
}

// ------- flash attention (R8 structure) + overlapped wo weight-packing -------
// Blocks 0..511: attention (qt x head-half x b), 4 waves = 4 heads, K/V LDS
// double-buffered XOR-swizzled, rank-paired, defer-max, paf butterfly, setprio.
// Blocks 512..6655: wo0/wo1 transpose-packs — memory-bound filler that drains
// into CU slots as short attention blocks finish (bto* consumed only by the
// NEXT launch, so same-stream ordering guarantees correctness).
__global__ __launch_bounds__(256, 2)
void k_attn(const US* __restrict__ qb, const US* __restrict__ kb,
            const US* __restrict__ vt, US* __restrict__ enc,
            const float* __restrict__ wo0, const float* __restrict__ wo1,
            US* __restrict__ bto0, US* __restrict__ bto1) {
  __shared__ __align__(16) US lK[2][32 * 256];   // 16KB x2
  __shared__ __align__(16) US lV[2][256 * 32];   // 16KB x2
  const int id = blockIdx.x;
  const int tid = threadIdx.x;

  if (id >= 512) {  // ---- wo pack path ----
    int local = id - 512;
    const float* src; US* dst; int C, CX;
    if (local < 4096) { src = wo0; dst = bto0; C = 2048; CX = 64; }
    else { local -= 4096; src = wo1; dst = bto1; C = 1024; CX = 32; }
    const int cx = local % CX, ry = local / CX;
    const int c0p = cx * 32, r0p = ry * 32;
    const int tx = tid & 31, ty = tid >> 5;
    float* tileF = (float*)&lK[0][0];  // 32x33 f32 aliases attn LDS
#pragma unroll
    for (int i = 0; i < 4; ++i)
      tileF[(ty + 8 * i) * 33 + tx] = src[(size_t)(r0p + ty + 8 * i) * C + c0p + tx];
    __syncthreads();
#pragma unroll
    for (int i = 0; i < 4; ++i)
      dst[(size_t)(c0p + ty + 8 * i) * 2048 + r0p + tx] = f2bf(tileF[tx * 33 + ty + 8 * i]);
    return;
  }

  // ---- attention path ----
  const int r0_ = (id < 256) ? id : 767 - id;    // work rank, descending length
  const int qt = 63 - (r0_ >> 3);
  const int hg = (r0_ >> 2) & 1;
  const int b = r0_ & 3;
  const int wid = tid >> 6;
  const int lane = tid & 63;
  const int g = lane >> 4, c = lane & 15;
  const int qbase = qt * 16;
  const int n = hg * 4 + wid;

  const US* kbB = kb + (size_t)b * 262144;
  const US* vtB = vt + (size_t)b * 262144;

  bf16x8 qf[8];
  {
    const US* qp = qb + ((size_t)((b * 1024 + qbase + c) * 8 + n)) * 256 + 8 * g;
#pragma unroll
    for (int ch = 0; ch < 8; ++ch)
      qf[ch] = *reinterpret_cast<const bf16x8*>(qp + ch * 32);
  }

  auto stage = [&](int bi, int c0) {
#pragma unroll
    for (int j = 0; j < 4; ++j) {
      const int rk = wid * 8 + j * 2 + (lane >> 5);
      const int sk = lane & 31;
      gld16(kbB + (size_t)(c0 + rk) * 256 + (sk ^ (rk & 7)) * 8,
            &lK[bi][(wid * 8 + j * 2) * 256]);
      const int rv = wid * 64 + j * 16 + (lane >> 2);
      const int sv = lane & 3;
      gld16(vtB + (size_t)rv * 1024 + c0 + (sv ^ ((rv >> 1) & 3)) * 8,
            &lV[bi][(wid * 64 + j * 16) * 32]);
    }
  };

  f32x4 acc[16];
#pragma unroll
  for (int i = 0; i < 16; ++i) acc[i] = f32x4{0.f, 0.f, 0.f, 0.f};
  float m_run = -3.0e38f, l_run = 0.f;

  const int nC = qbase / 32 + 1;
  stage(0, 0);
  __syncthreads();

  for (int i = 0; i < nC; ++i) {
    const int c0 = 32 * i;
    const int bi = i & 1;
    if (i + 1 < nC) stage(bi ^ 1, c0 + 32);

    const bool hb = (c0 + 16 <= qbase);
    f32x4 sA = {0.f, 0.f, 0.f, 0.f}, sB = {0.f, 0.f, 0.f, 0.f};
    __builtin_amdgcn_s_setprio(1);
#pragma unroll
    for (int ch = 0; ch < 8; ++ch) {
      const int slot = (((ch * 4 + g) ^ (c & 7)) * 8);
      sA = mfma16(*reinterpret_cast<const bf16x8*>(&lK[bi][c * 256 + slot]), qf[ch], sA);
    }
    if (hb) {
#pragma unroll
      for (int ch = 0; ch < 8; ++ch) {
        const int slot = (((ch * 4 + g) ^ (c & 7)) * 8);  // (c+16)&7 == c&7
        sB = mfma16(*reinterpret_cast<const bf16x8*>(&lK[bi][(c + 16) * 256 + slot]), qf[ch], sB);
      }
    }
    __builtin_amdgcn_s_setprio(0);
    if (c0 == qbase) {
#pragma unroll
      for (int r = 0; r < 4; ++r)
        if (4 * g + r > c) sA[r] = -3.0e38f;
    }
    if (hb && (c0 + 16 == qbase)) {
#pragma unroll
      for (int r = 0; r < 4; ++r)
        if (4 * g + r > c) sB[r] = -3.0e38f;
    }
    float tm = fmaxf(fmaxf(sA[0], sA[1]), fmaxf(sA[2], sA[3]));
    if (hb) tm = fmaxf(tm, fmaxf(fmaxf(sB[0], sB[1]), fmaxf(sB[2], sB[3])));
    tm = fmaxf(tm, __shfl_xor(tm, 16));
    tm = fmaxf(tm, __shfl_xor(tm, 32));
    // defer-max: only rescale when the running max actually grows past THR
    if (!__all(tm - m_run <= 8.0f)) {
      const float m_new = fmaxf(m_run, tm);
      const float alpha = __expf(m_run - m_new);
      float aacc[4];
#pragma unroll
      for (int r = 0; r < 4; ++r) aacc[r] = __shfl(alpha, 4 * g + r);
#pragma unroll
      for (int ht = 0; ht < 16; ++ht) {
        acc[ht][0] *= aacc[0]; acc[ht][1] *= aacc[1];
        acc[ht][2] *= aacc[2]; acc[ht][3] *= aacc[3];
      }
      l_run *= alpha;
      m_run = m_new;
    }
    float pA[4], pB[4];
    float ls = 0.f;
#pragma unroll
    for (int r = 0; r < 4; ++r) { pA[r] = __expf(sA[r] - m_run); ls += pA[r]; }
#pragma unroll
    for (int r = 0; r < 4; ++r) { pB[r] = hb ? __expf(sB[r] - m_run) : 0.f; ls += pB[r]; }
    ls += __shfl_xor(ls, 16);
    ls += __shfl_xor(ls, 32);
    l_run += ls;

    // --- paf butterfly: pack P to bf16 pairs, then 2-stage 4-lane-group transpose ---
    unsigned w0, w1, w2, w3;
    asm("v_cvt_pk_bf16_f32 %0, %1, %2" : "=v"(w0) : "v"(pA[0]), "v"(pA[1]));
    asm("v_cvt_pk_bf16_f32 %0, %1, %2" : "=v"(w1) : "v"(pA[2]), "v"(pA[3]));
    asm("v_cvt_pk_bf16_f32 %0, %1, %2" : "=v"(w2) : "v"(pB[0]), "v"(pB[1]));
    asm("v_cvt_pk_bf16_f32 %0, %1, %2" : "=v"(w3) : "v"(pB[2]), "v"(pB[3]));
    const bool bb1 = ((g >> 1) & 1) != 0, bb0 = (g & 1) != 0;
    unsigned ownA = bb1 ? w2 : w0, ownB = bb1 ? w3 : w1;
    unsigned sndA = bb1 ? w0 : w2, sndB = bb1 ? w1 : w3;
    unsigned rcvA = (unsigned)__shfl_xor((int)sndA, 32);
    unsigned rcvB = (unsigned)__shfl_xor((int)sndB, 32);
    unsigned kA = (bb0 == bb1) ? ownA : rcvA, kB = (bb0 == bb1) ? ownB : rcvB;
    unsigned s2A = (bb0 == bb1) ? rcvA : ownA, s2B = (bb0 == bb1) ? rcvB : ownB;
    unsigned gA = (unsigned)__shfl_xor((int)s2A, 16);
    unsigned gB = (unsigned)__shfl_xor((int)s2B, 16);
    union { unsigned u[4]; bf16x8 v; } pu;
    pu.u[0] = bb0 ? gA : kA; pu.u[1] = bb0 ? gB : kB;
    pu.u[2] = bb0 ? kA : gA; pu.u[3] = bb0 ? kB : gB;
    const bf16x8 paf = pu.v;

    __builtin_amdgcn_s_setprio(1);
#pragma unroll
    for (int ht = 0; ht < 16; ++ht) {
      const int h = ht * 16 + c;
      const int slot = (g ^ ((c >> 1) & 3)) * 8;
      bf16x8 vf = *reinterpret_cast<const bf16x8*>(&lV[bi][h * 32 + slot]);
      acc[ht] = mfma16(paf, vf, acc[ht]);
    }
    __builtin_amdgcn_s_setprio(0);
    __syncthreads();  // buf[bi] reads done; staging of buf[bi^1] drained
  }

  const float inv = 1.0f / l_run;
  float ia[4];
#pragma unroll
  for (int r = 0; r < 4; ++r) ia[r] = __shfl(inv, 4 * g + r);
#pragma unroll
  for (int ht = 0; ht < 16; ++ht) {
#pragma unroll
    for (int r = 0; r < 4; ++r) {
      size_t o = ((size_t)((b * 1024 + qbase + 4 * g + r) * 8 + n)) * 256 + ht * 16 + c;
      enc[o] = f2bf(acc[ht][r] * ia[r]);
    }
  }
}

extern "C" void kernel_launch(void* const* d_in, const int* in_sizes, int n_in,
                              void* d_out, int out_size, void* d_ws, size_t ws_size,
                              hipStream_t stream) {
  const float* x0 = (const float*)d_in[0];
  const float* x1 = (const float*)d_in[1];
  const float* wq0 = (const float*)d_in[2];
  const float* wkv0 = (const float*)d_in[3];
  const float* wo0 = (const float*)d_in[4];
  const float* wq1 = (const float*)d_in[5];
  const float* wkv1 = (const float*)d_in[6];
  const float* wo1 = (const float*)d_in[7];
  const int* pos = (const int*)d_in[8];
  float* out = (float*)d_out;

  float* out0 = out;                    // 4*768*2048
  float* out1 = out + 6291456;          // 4*256*1024
  float* k_out = out + 7340032;         // 4*1024*256
  float* v_out = out + 8388608;         // 4*1024*256

  char* ws = (char*)d_ws;
  size_t off = 0;
  auto alloc = [&](size_t bytes) {
    char* p = ws + off;
    off += (bytes + 255) & ~(size_t)255;
    return p;
  };
  US* x0b   = (US*)alloc(6291456ull * 2);
  US* x1b   = (US*)alloc(1048576ull * 2);
  US* btq0  = (US*)alloc(2048ull * 2048 * 2);   // btq0+btkv0 contiguous: [2560][2048]
  US* btkv0 = (US*)alloc(512ull * 2048 * 2);
  US* btq1  = (US*)alloc(2048ull * 1024 * 2);   // btq1+btkv1 contiguous: [2560][1024]
  US* btkv1 = (US*)alloc(512ull * 1024 * 2);
  US* bto0  = (US*)alloc(2048ull * 2048 * 2);
  US* bto1  = (US*)alloc(1024ull * 2048 * 2);
  float* kv_raw = (float*)alloc(2097152ull * 4);
  US* q_bf = (US*)alloc(8388608ull * 2);
  US* k_bf = (US*)alloc(1048576ull * 2);
  US* vt   = (US*)alloc(1048576ull * 2 + 256);
  US* enc  = (US*)alloc(8388608ull * 2);
  float2* sct = (float2*)alloc(524288ull * 8);
  (void)btkv0; (void)btkv1;

  // phase 1: fused casts + qkv weight packs + sin/cos table
  k_prep<<<16896, 256, 0, stream>>>(x0, x1, x0b, x1b, wq0, wkv0, wq1, wkv1,
                                    btq0, btkv0, btq1, btkv1, pos, sct);

  // phase 2: merged QKV projection GEMMs (both streams, RoPE-q fused epilogue)
  k_gemm_qkv<<<640, 256, 0, stream>>>(x0b, x1b, btq0, btq1, q_bf, kv_raw, sct);

  // phase 3: merged k-RoPE + V transpose (emit k, v fp32 outputs)
  k_postkv<<<3072, 256, 0, stream>>>(kv_raw, sct, k_bf, k_out, v_out, vt);

  // phase 4: causal flash attention + overlapped wo0/wo1 weight packs
  k_attn<<<6656, 256, 0, stream>>>(q_bf, k_bf, vt, enc, wo0, wo1, bto0, bto1);

  // phase 5: compact fused output GEMM (448 tiles, no holes)
  k_gemm_out<<<448, 256, 0, stream>>>(enc, bto0, bto1, out0, out1);
}

// Round 11
// 188.926 us; speedup vs baseline: 1.0762x; 1.0082x over previous
//
#include <hip/hip_runtime.h>
#include <hip/hip_bf16.h>

typedef __attribute__((ext_vector_type(8))) short bf16x8;
typedef __attribute__((ext_vector_type(4))) float f32x4;
typedef __attribute__((ext_vector_type(4))) unsigned short u16x4;
typedef unsigned short US;

__device__ __forceinline__ f32x4 mfma16(bf16x8 a, bf16x8 b, f32x4 c) {
  return __builtin_amdgcn_mfma_f32_16x16x32_bf16(a, b, c, 0, 0, 0);
}

__device__ __forceinline__ US f2bf(float f) {
  union { float f; unsigned u; } x; x.f = f;
  unsigned r = x.u + 0x7fffu + ((x.u >> 16) & 1u);
  return (US)(r >> 16);
}

// async global->LDS, 16B per lane; LDS dest = wave-uniform base + lane*16
__device__ __forceinline__ void gld16(const US* gp, US* lp) {
  __builtin_amdgcn_global_load_lds(
      (const __attribute__((address_space(1))) unsigned*)gp,
      (__attribute__((address_space(3))) unsigned*)lp, 16, 0, 0);
}

// RoPE column permutation: logical h (0..127) -> physical p; partner h+128 -> p+16.
__device__ __forceinline__ int permq(int h) {  // h in [0,128)
  return ((h >> 5) << 6) + (h & 15) + (((h >> 4) & 1) << 5);
}

// row remap fusing the time-concat: mode1: r=b*768+s -> b*1024+s ; mode2: r=b*256+s -> b*1024+768+s
__device__ __forceinline__ int map_row(int r, int mode) {
  if (mode == 1) { int b = r / 768; return b * 1024 + (r - b * 768); }
  if (mode == 2) { int b = r >> 8; return b * 1024 + 768 + (r & 255); }
  return r;
}

// ------- fused prep: casts + qkv weight transpose-packs + sin/cos table -------
// (wo0/wo1 packs live in the k_attn launch to overlap with attention)
__global__ __launch_bounds__(256)
void k_prep(const float* __restrict__ x0, const float* __restrict__ x1,
            US* __restrict__ x0b, US* __restrict__ x1b,
            const float* __restrict__ wq0, const float* __restrict__ wkv0,
            const float* __restrict__ wq1, const float* __restrict__ wkv1,
            US* __restrict__ btq0, US* __restrict__ btkv0,
            US* __restrict__ btq1, US* __restrict__ btkv1,
            const int* __restrict__ pos, float2* __restrict__ sct) {
  const int bid = blockIdx.x;
  const int tid = threadIdx.x;
  if (bid >= 14848) {  // sin/cos table: 2048 blocks, 512K entries
    int idx = (bid - 14848) * 256 + tid;
    int bt = idx >> 7, j = idx & 127;
    // inv_ts = 10000^(-j/128) = exp(-ln(1e4)/128 * j); HW-rate intrinsics:
    // error ~5e-4 rad at p~1e3 -> sin/cos err ~5e-4, << bf16 quantum (4e-3).
    float inv_ts = __expf(-0.0719557841f * (float)j);
    float r = (float)pos[bt] * inv_ts;
    float s, co;
    __sincosf(r, &s, &co);
    sct[idx] = make_float2(s, co);
    return;
  }
  if (bid < 7168) {  // bf16 casts
    const float* src; US* dst; int i;
    if (bid < 6144) { src = x0; dst = x0b; i = bid * 256 + tid; }
    else            { src = x1; dst = x1b; i = (bid - 6144) * 256 + tid; }
    f32x4 v = *reinterpret_cast<const f32x4*>(src + (size_t)i * 4);
    u16x4 o;
    o[0] = f2bf(v[0]); o[1] = f2bf(v[1]); o[2] = f2bf(v[2]); o[3] = f2bf(v[3]);
    *reinterpret_cast<u16x4*>(dst + (size_t)i * 4) = o;
    return;
  }
  __shared__ float tile[32][33];
  const float* src; US* dst; int R, C, CX, local; long sbs, dbs; bool pq = false;
  if (bid < 11264)      { local = bid - 7168;  src = wq0;  dst = btq0;  R = 2048; C = 256; CX = 8; sbs = 2048L * 256; dbs = 256L * 2048; pq = true; }
  else if (bid < 12288) { local = bid - 11264; src = wkv0; dst = btkv0; R = 2048; C = 256; CX = 8; sbs = 2048L * 256; dbs = 256L * 2048; }
  else if (bid < 14336) { local = bid - 12288; src = wq1;  dst = btq1;  R = 1024; C = 256; CX = 8; sbs = 1024L * 256; dbs = 256L * 1024; pq = true; }
  else                  { local = bid - 14336; src = wkv1; dst = btkv1; R = 1024; C = 256; CX = 8; sbs = 1024L * 256; dbs = 256L * 1024; }
  const int RY = R >> 5;
  const int cx = local % CX;
  const int rest = local / CX;
  const int ry = rest % RY;
  const int z = rest / RY;
  const int c0 = cx * 32, r0 = ry * 32;
  const int tx = tid & 31, ty = tid >> 5;
  src += (long)z * sbs;
  dst += (long)z * dbs;
#pragma unroll
  for (int i = 0; i < 4; ++i)
    tile[ty + 8 * i][tx] = src[(size_t)(r0 + ty + 8 * i) * C + c0 + tx];
  __syncthreads();
#pragma unroll
  for (int i = 0; i < 4; ++i) {
    int h = c0 + ty + 8 * i;
    int ph = pq ? ((h < 128) ? permq(h) : permq(h - 128) + 16) : h;
    dst[(size_t)ph * R + r0 + tx] = f2bf(tile[tx][ty + 8 * i]);
  }
}

// ------- merged QKV projection GEMM (both streams, one launch, XCD-swizzled) -------
__global__ __launch_bounds__(256, 2)
void k_gemm_qkv(const US* __restrict__ x0b, const US* __restrict__ x1b,
                const US* __restrict__ btq0, const US* __restrict__ btq1,
                US* __restrict__ q_bf, float* __restrict__ Ckv,
                const float2* __restrict__ sct) {
  const int bid = blockIdx.x;
  int id = (bid & 7) * 80 + (bid >> 3);   // bijective XCD swizzle (640 = 8*80)
  const US* A; const US* BT; int K, cmap, by, bx;
  if (id < 480) { A = x0b; BT = btq0; K = 2048; cmap = 1; by = id / 20; bx = id % 20; }
  else { id -= 480; A = x1b; BT = btq1; K = 1024; cmap = 2; by = id / 20; bx = id % 20; }

  __shared__ __align__(16) US lA[2][128 * 32];
  __shared__ __align__(16) US lB[2][128 * 32];
  const int tid = threadIdx.x;
  const int lane = tid & 63;
  const int wid = tid >> 6;
  const int wm = wid >> 1, wn = wid & 1;
  const int m0 = by * 128, n0 = bx * 128;
  const int g = lane >> 4, c = lane & 15;
  const int lrow = lane >> 2, lcol = (lane & 3) * 8;
  const size_t ga0 = (size_t)(m0 + wid * 16 + lrow) * K + lcol;
  const size_t ga1 = (size_t)(m0 + 64 + wid * 16 + lrow) * K + lcol;
  const size_t gb0 = (size_t)(n0 + wid * 16 + lrow) * K + lcol;
  const size_t gb1 = (size_t)(n0 + 64 + wid * 16 + lrow) * K + lcol;

  auto stage = [&](int bi, int k0) {
    gld16(A + ga0 + k0, &lA[bi][(wid * 16) * 32]);
    gld16(A + ga1 + k0, &lA[bi][(64 + wid * 16) * 32]);
    gld16(BT + gb0 + k0, &lB[bi][(wid * 16) * 32]);
    gld16(BT + gb1 + k0, &lB[bi][(64 + wid * 16) * 32]);
  };

  f32x4 acc[4][4];
#pragma unroll
  for (int i = 0; i < 4; ++i)
#pragma unroll
    for (int j = 0; j < 4; ++j) acc[i][j] = f32x4{0.f, 0.f, 0.f, 0.f};

  const int nt = K >> 5;
  stage(0, 0);
  __syncthreads();
  for (int t = 0; t < nt; ++t) {
    const int bi = t & 1;
    if (t + 1 < nt) stage(bi ^ 1, (t + 1) * 32);
    bf16x8 af[4], bfr[4];
#pragma unroll
    for (int i = 0; i < 4; ++i) {
      af[i] = *reinterpret_cast<const bf16x8*>(&lA[bi][(wm * 64 + i * 16 + c) * 32 + g * 8]);
      bfr[i] = *reinterpret_cast<const bf16x8*>(&lB[bi][(wn * 64 + i * 16 + c) * 32 + g * 8]);
    }
#pragma unroll
    for (int i = 0; i < 4; ++i)
#pragma unroll
      for (int j = 0; j < 4; ++j)
        acc[i][j] = mfma16(af[i], bfr[j], acc[i][j]);
    __syncthreads();  // drains vmcnt(0): prefetch landed; buf[bi] reads done
  }

  const int colb = n0 + wn * 64;
  if (colb < 2048) {
    // q path: RoPE + scale -> bf16 (permuted layout; pairs are (j0,j1),(j2,j3))
    const int n = colb >> 8;
    const int base64 = colb & 255;
    const int h0 = (base64 >> 6) * 32 + c;
    const float scale = 0.0625f;
#pragma unroll
    for (int i = 0; i < 4; ++i) {
#pragma unroll
      for (int r = 0; r < 4; ++r) {
        const int orow = map_row(m0 + wm * 64 + i * 16 + 4 * g + r, cmap);
        const float2 sc0 = sct[orow * 128 + h0];
        const float2 sc1 = sct[orow * 128 + h0 + 16];
        US* qp = q_bf + ((size_t)orow * 8 + n) * 256 + base64 + c;
        const float q1 = acc[i][0][r], q2 = acc[i][1][r];
        const float q3 = acc[i][2][r], q4 = acc[i][3][r];
        qp[0]  = f2bf(scale * (q1 * sc0.y - q2 * sc0.x));
        qp[16] = f2bf(scale * (q2 * sc0.y + q1 * sc0.x));
        qp[32] = f2bf(scale * (q3 * sc1.y - q4 * sc1.x));
        qp[48] = f2bf(scale * (q4 * sc1.y + q3 * sc1.x));
      }
    }
  } else {
    const int nb = colb - 2048 + c;
#pragma unroll
    for (int i = 0; i < 4; ++i) {
#pragma unroll
      for (int r = 0; r < 4; ++r) {
        const int orow = map_row(m0 + wm * 64 + i * 16 + 4 * g + r, cmap);
        float* cp = Ckv + (size_t)orow * 512 + nb;
#pragma unroll
        for (int j = 0; j < 4; ++j) cp[j * 16] = acc[i][j][r];
      }
    }
  }
}

// ------- compact output GEMM: 448 tiles (384 out0 + 64 out1), XCD-swizzled -------
__global__ __launch_bounds__(256, 2)
void k_gemm_out(const US* __restrict__ A, const US* __restrict__ BT0, const US* __restrict__ BT1,
                float* __restrict__ C0, float* __restrict__ C1) {
  const int bid = blockIdx.x;
  int id = (bid & 7) * 56 + (bid >> 3);   // bijective XCD swizzle (448 = 8*56)
  const US* BT; float* Cb; int amap, mt, ntile, Nst;
  if (id < 384) { amap = 1; mt = id / 16; ntile = id % 16; BT = BT0; Cb = C0; Nst = 2048; }
  else { id -= 384; amap = 2; mt = id / 8; ntile = id % 8; BT = BT1; Cb = C1; Nst = 1024; }
  const int m0 = mt * 128, n0 = ntile * 128;
  const int K = 2048;
  __shared__ __align__(16) US lA[2][128 * 32];
  __shared__ __align__(16) US lB[2][128 * 32];
  const int tid = threadIdx.x;
  const int lane = tid & 63;
  const int wid = tid >> 6;
  const int wm = wid >> 1, wn = wid & 1;
  const int g = lane >> 4, c = lane & 15;
  const int lrow = lane >> 2, lcol = (lane & 3) * 8;
  const size_t ga0 = (size_t)map_row(m0 + wid * 16 + lrow, amap) * K + lcol;
  const size_t ga1 = (size_t)map_row(m0 + 64 + wid * 16 + lrow, amap) * K + lcol;
  const size_t gb0 = (size_t)(n0 + wid * 16 + lrow) * K + lcol;
  const size_t gb1 = (size_t)(n0 + 64 + wid * 16 + lrow) * K + lcol;

  auto stage = [&](int bi, int k0) {
    gld16(A + ga0 + k0, &lA[bi][(wid * 16) * 32]);
    gld16(A + ga1 + k0, &lA[bi][(64 + wid * 16) * 32]);
    gld16(BT + gb0 + k0, &lB[bi][(wid * 16) * 32]);
    gld16(BT + gb1 + k0, &lB[bi][(64 + wid * 16) * 32]);
  };

  f32x4 acc[4][4];
#pragma unroll
  for (int i = 0; i < 4; ++i)
#pragma unroll
    for (int j = 0; j < 4; ++j) acc[i][j] = f32x4{0.f, 0.f, 0.f, 0.f};

  const int nt = K >> 5;
  stage(0, 0);
  __syncthreads();
  for (int t = 0; t < nt; ++t) {
    const int bi = t & 1;
    if (t + 1 < nt) stage(bi ^ 1, (t + 1) * 32);
    bf16x8 af[4], bfr[4];
#pragma unroll
    for (int i = 0; i < 4; ++i) {
      af[i] = *reinterpret_cast<const bf16x8*>(&lA[bi][(wm * 64 + i * 16 + c) * 32 + g * 8]);
      bfr[i] = *reinterpret_cast<const bf16x8*>(&lB[bi][(wn * 64 + i * 16 + c) * 32 + g * 8]);
    }
#pragma unroll
    for (int i = 0; i < 4; ++i)
#pragma unroll
      for (int j = 0; j < 4; ++j)
        acc[i][j] = mfma16(af[i], bfr[j], acc[i][j]);
    __syncthreads();
  }

  const int col = n0 + wn * 64 + c;
#pragma unroll
  for (int i = 0; i < 4; ++i) {
#pragma unroll
    for (int r = 0; r < 4; ++r) {
      const int orow = m0 + wm * 64 + i * 16 + 4 * g + r;  // compact per-segment row
      float* cp = Cb + (size_t)orow * Nst + col;
#pragma unroll
      for (int j = 0; j < 4; ++j) cp[j * 16] = acc[i][j][r];
    }
  }
}

// ------- merged post-KV: V transpose (+v_out) and k-RoPE (+k_out) in one launch -------
__global__ __launch_bounds__(256)
void k_postkv(const float* __restrict__ kv_raw, const float2* __restrict__ sct,
              US* __restrict__ k_bf, float* __restrict__ k_out,
              float* __restrict__ v_out, US* __restrict__ vt) {
  const int bid = blockIdx.x;
  const int tid = threadIdx.x;
  if (bid >= 1024) {  // k-RoPE: 2048 blocks, 2 bt-rows each
    const int bt = (bid - 1024) * 2 + (tid >> 7);
    const int j = tid & 127;
    const size_t ko = (size_t)bt * 512;
    const float x1 = kv_raw[ko + j], x2 = kv_raw[ko + j + 128];
    const float2 sc = sct[bt * 128 + j];
    const float o1 = x1 * sc.y - x2 * sc.x, o2 = x2 * sc.y + x1 * sc.x;
    const size_t kd = (size_t)bt * 256;
    const int p = permq(j);
    k_bf[kd + p] = f2bf(o1);
    k_bf[kd + p + 16] = f2bf(o2);
    k_out[kd + j] = o1;
    k_out[kd + j + 128] = o2;
    return;
  }
  __shared__ float tile[32][33];
  const int t0 = (bid & 31) * 32, h0 = ((bid >> 5) & 7) * 32, b = bid >> 8;
  const int tx = tid & 31, ty = tid >> 5;
#pragma unroll
  for (int i = 0; i < 4; ++i) {
    int t = t0 + ty + 8 * i;
    float v = kv_raw[(size_t)(b * 1024 + t) * 512 + 256 + h0 + tx];
    tile[ty + 8 * i][tx] = v;
    v_out[(size_t)(b * 1024 + t) * 256 + h0 + tx] = v;
  }
  __syncthreads();
#pragma unroll
  for (int i = 0; i < 4; ++i) {
    int h = h0 + ty + 8 * i;
    vt[(size_t)(b * 256 + h) * 1024 + t0 + tx] = f2bf(tile[tx][ty + 8 * i]);
  }
}

// ------- flash attention (R8 structure) + overlapped wo weight-packing -------
__global__ __launch_bounds__(256, 2)
void k_attn(const US* __restrict__ qb, const US* __restrict__ kb,
            const US* __restrict__ vt, US* __restrict__ enc,
            const float* __restrict__ wo0, const float* __restrict__ wo1,
            US* __restrict__ bto0, US* __restrict__ bto1) {
  __shared__ __align__(16) US lK[2][32 * 256];   // 16KB x2
  __shared__ __align__(16) US lV[2][256 * 32];   // 16KB x2
  const int id = blockIdx.x;
  const int tid = threadIdx.x;

  if (id >= 512) {  // ---- wo pack path ----
    int local = id - 512;
    const float* src; US* dst; int C, CX;
    if (local < 4096) { src = wo0; dst = bto0; C = 2048; CX = 64; }
    else { local -= 4096; src = wo1; dst = bto1; C = 1024; CX = 32; }
    const int cx = local % CX, ry = local / CX;
    const int c0p = cx * 32, r0p = ry * 32;
    const int tx = tid & 31, ty = tid >> 5;
    float* tileF = (float*)&lK[0][0];  // 32x33 f32 aliases attn LDS
#pragma unroll
    for (int i = 0; i < 4; ++i)
      tileF[(ty + 8 * i) * 33 + tx] = src[(size_t)(r0p + ty + 8 * i) * C + c0p + tx];
    __syncthreads();
#pragma unroll
    for (int i = 0; i < 4; ++i)
      dst[(size_t)(c0p + ty + 8 * i) * 2048 + r0p + tx] = f2bf(tileF[tx * 33 + ty + 8 * i]);
    return;
  }

  // ---- attention path ----
  const int r0_ = (id < 256) ? id : 767 - id;    // work rank, descending length
  const int qt = 63 - (r0_ >> 3);
  const int hg = (r0_ >> 2) & 1;
  const int b = r0_ & 3;
  const int wid = tid >> 6;
  const int lane = tid & 63;
  const int g = lane >> 4, c = lane & 15;
  const int qbase = qt * 16;
  const int n = hg * 4 + wid;

  const US* kbB = kb + (size_t)b * 262144;
  const US* vtB = vt + (size_t)b * 262144;

  bf16x8 qf[8];
  {
    const US* qp = qb + ((size_t)((b * 1024 + qbase + c) * 8 + n)) * 256 + 8 * g;
#pragma unroll
    for (int ch = 0; ch < 8; ++ch)
      qf[ch] = *reinterpret_cast<const bf16x8*>(qp + ch * 32);
  }

  auto stage = [&](int bi, int c0) {
#pragma unroll
    for (int j = 0; j < 4; ++j) {
      const int rk = wid * 8 + j * 2 + (lane >> 5);
      const int sk = lane & 31;
      gld16(kbB + (size_t)(c0 + rk) * 256 + (sk ^ (rk & 7)) * 8,
            &lK[bi][(wid * 8 + j * 2) * 256]);
      const int rv = wid * 64 + j * 16 + (lane >> 2);
      const int sv = lane & 3;
      gld16(vtB + (size_t)rv * 1024 + c0 + (sv ^ ((rv >> 1) & 3)) * 8,
            &lV[bi][(wid * 64 + j * 16) * 32]);
    }
  };

  f32x4 acc[16];
#pragma unroll
  for (int i = 0; i < 16; ++i) acc[i] = f32x4{0.f, 0.f, 0.f, 0.f};
  float m_run = -3.0e38f, l_run = 0.f;

  const int nC = qbase / 32 + 1;
  stage(0, 0);
  __syncthreads();

  for (int i = 0; i < nC; ++i) {
    const int c0 = 32 * i;
    const int bi = i & 1;
    if (i + 1 < nC) stage(bi ^ 1, c0 + 32);

    const bool hb = (c0 + 16 <= qbase);
    f32x4 sA = {0.f, 0.f, 0.f, 0.f}, sB = {0.f, 0.f, 0.f, 0.f};
    __builtin_amdgcn_s_setprio(1);
#pragma unroll
    for (int ch = 0; ch < 8; ++ch) {
      const int slot = (((ch * 4 + g) ^ (c & 7)) * 8);
      sA = mfma16(*reinterpret_cast<const bf16x8*>(&lK[bi][c * 256 + slot]), qf[ch], sA);
    }
    if (hb) {
#pragma unroll
      for (int ch = 0; ch < 8; ++ch) {
        const int slot = (((ch * 4 + g) ^ (c & 7)) * 8);  // (c+16)&7 == c&7
        sB = mfma16(*reinterpret_cast<const bf16x8*>(&lK[bi][(c + 16) * 256 + slot]), qf[ch], sB);
      }
    }
    __builtin_amdgcn_s_setprio(0);
    if (c0 == qbase) {
#pragma unroll
      for (int r = 0; r < 4; ++r)
        if (4 * g + r > c) sA[r] = -3.0e38f;
    }
    if (hb && (c0 + 16 == qbase)) {
#pragma unroll
      for (int r = 0; r < 4; ++r)
        if (4 * g + r > c) sB[r] = -3.0e38f;
    }
    float tm = fmaxf(fmaxf(sA[0], sA[1]), fmaxf(sA[2], sA[3]));
    if (hb) tm = fmaxf(tm, fmaxf(fmaxf(sB[0], sB[1]), fmaxf(sB[2], sB[3])));
    tm = fmaxf(tm, __shfl_xor(tm, 16));
    tm = fmaxf(tm, __shfl_xor(tm, 32));
    // defer-max: only rescale when the running max actually grows past THR
    if (!__all(tm - m_run <= 8.0f)) {
      const float m_new = fmaxf(m_run, tm);
      const float alpha = __expf(m_run - m_new);
      float aacc[4];
#pragma unroll
      for (int r = 0; r < 4; ++r) aacc[r] = __shfl(alpha, 4 * g + r);
#pragma unroll
      for (int ht = 0; ht < 16; ++ht) {
        acc[ht][0] *= aacc[0]; acc[ht][1] *= aacc[1];
        acc[ht][2] *= aacc[2]; acc[ht][3] *= aacc[3];
      }
      l_run *= alpha;
      m_run = m_new;
    }
    float pA[4], pB[4];
    float ls = 0.f;
#pragma unroll
    for (int r = 0; r < 4; ++r) { pA[r] = __expf(sA[r] - m_run); ls += pA[r]; }
#pragma unroll
    for (int r = 0; r < 4; ++r) { pB[r] = hb ? __expf(sB[r] - m_run) : 0.f; ls += pB[r]; }
    ls += __shfl_xor(ls, 16);
    ls += __shfl_xor(ls, 32);
    l_run += ls;

    // --- paf butterfly: pack P to bf16 pairs, then 2-stage 4-lane-group transpose ---
    unsigned w0, w1, w2, w3;
    asm("v_cvt_pk_bf16_f32 %0, %1, %2" : "=v"(w0) : "v"(pA[0]), "v"(pA[1]));
    asm("v_cvt_pk_bf16_f32 %0, %1, %2" : "=v"(w1) : "v"(pA[2]), "v"(pA[3]));
    asm("v_cvt_pk_bf16_f32 %0, %1, %2" : "=v"(w2) : "v"(pB[0]), "v"(pB[1]));
    asm("v_cvt_pk_bf16_f32 %0, %1, %2" : "=v"(w3) : "v"(pB[2]), "v"(pB[3]));
    const bool bb1 = ((g >> 1) & 1) != 0, bb0 = (g & 1) != 0;
    unsigned ownA = bb1 ? w2 : w0, ownB = bb1 ? w3 : w1;
    unsigned sndA = bb1 ? w0 : w2, sndB = bb1 ? w1 : w3;
    unsigned rcvA = (unsigned)__shfl_xor((int)sndA, 32);
    unsigned rcvB = (unsigned)__shfl_xor((int)sndB, 32);
    unsigned kA = (bb0 == bb1) ? ownA : rcvA, kB = (bb0 == bb1) ? ownB : rcvB;
    unsigned s2A = (bb0 == bb1) ? rcvA : ownA, s2B = (bb0 == bb1) ? rcvB : ownB;
    unsigned gA = (unsigned)__shfl_xor((int)s2A, 16);
    unsigned gB = (unsigned)__shfl_xor((int)s2B, 16);
    union { unsigned u[4]; bf16x8 v; } pu;
    pu.u[0] = bb0 ? gA : kA; pu.u[1] = bb0 ? gB : kB;
    pu.u[2] = bb0 ? kA : gA; pu.u[3] = bb0 ? kB : gB;
    const bf16x8 paf = pu.v;

    __builtin_amdgcn_s_setprio(1);
#pragma unroll
    for (int ht = 0; ht < 16; ++ht) {
      const int h = ht * 16 + c;
      const int slot = (g ^ ((c >> 1) & 3)) * 8;
      bf16x8 vf = *reinterpret_cast<const bf16x8*>(&lV[bi][h * 32 + slot]);
      acc[ht] = mfma16(paf, vf, acc[ht]);
    }
    __builtin_amdgcn_s_setprio(0);
    __syncthreads();  // buf[bi] reads done; staging of buf[bi^1] drained
  }

  const float inv = 1.0f / l_run;
  float ia[4];
#pragma unroll
  for (int r = 0; r < 4; ++r) ia[r] = __shfl(inv, 4 * g + r);
#pragma unroll
  for (int ht = 0; ht < 16; ++ht) {
#pragma unroll
    for (int r = 0; r < 4; ++r) {
      size_t o = ((size_t)((b * 1024 + qbase + 4 * g + r) * 8 + n)) * 256 + ht * 16 + c;
      enc[o] = f2bf(acc[ht][r] * ia[r]);
    }
  }
}

extern "C" void kernel_launch(void* const* d_in, const int* in_sizes, int n_in,
                              void* d_out, int out_size, void* d_ws, size_t ws_size,
                              hipStream_t stream) {
  const float* x0 = (const float*)d_in[0];
  const float* x1 = (const float*)d_in[1];
  const float* wq0 = (const float*)d_in[2];
  const float* wkv0 = (const float*)d_in[3];
  const float* wo0 = (const float*)d_in[4];
  const float* wq1 = (const float*)d_in[5];
  const float* wkv1 = (const float*)d_in[6];
  const float* wo1 = (const float*)d_in[7];
  const int* pos = (const int*)d_in[8];
  float* out = (float*)d_out;

  float* out0 = out;                    // 4*768*2048
  float* out1 = out + 6291456;          // 4*256*1024
  float* k_out = out + 7340032;         // 4*1024*256
  float* v_out = out + 8388608;         // 4*1024*256

  char* ws = (char*)d_ws;
  size_t off = 0;
  auto alloc = [&](size_t bytes) {
    char* p = ws + off;
    off += (bytes + 255) & ~(size_t)255;
    return p;
  };
  US* x0b   = (US*)alloc(6291456ull * 2);
  US* x1b   = (US*)alloc(1048576ull * 2);
  US* btq0  = (US*)alloc(2048ull * 2048 * 2);   // btq0+btkv0 contiguous: [2560][2048]
  US* btkv0 = (US*)alloc(512ull * 2048 * 2);
  US* btq1  = (US*)alloc(2048ull * 1024 * 2);   // btq1+btkv1 contiguous: [2560][1024]
  US* btkv1 = (US*)alloc(512ull * 1024 * 2);
  US* bto0  = (US*)alloc(2048ull * 2048 * 2);
  US* bto1  = (US*)alloc(1024ull * 2048 * 2);
  float* kv_raw = (float*)alloc(2097152ull * 4);
  US* q_bf = (US*)alloc(8388608ull * 2);
  US* k_bf = (US*)alloc(1048576ull * 2);
  US* vt   = (US*)alloc(1048576ull * 2 + 256);
  US* enc  = (US*)alloc(8388608ull * 2);
  float2* sct = (float2*)alloc(524288ull * 8);
  (void)btkv0; (void)btkv1;

  // phase 1: fused casts + qkv weight packs + sin/cos table (fast intrinsics)
  k_prep<<<16896, 256, 0, stream>>>(x0, x1, x0b, x1b, wq0, wkv0, wq1, wkv1,
                                    btq0, btkv0, btq1, btkv1, pos, sct);

  // phase 2: merged QKV projection GEMMs (both streams, RoPE-q fused epilogue)
  k_gemm_qkv<<<640, 256, 0, stream>>>(x0b, x1b, btq0, btq1, q_bf, kv_raw, sct);

  // phase 3: merged k-RoPE + V transpose (emit k, v fp32 outputs)
  k_postkv<<<3072, 256, 0, stream>>>(kv_raw, sct, k_bf, k_out, v_out, vt);

  // phase 4: causal flash attention + overlapped wo0/wo1 weight packs
  k_attn<<<6656, 256, 0, stream>>>(q_bf, k_bf, vt, enc, wo0, wo1, bto0, bto1);

  // phase 5: compact fused output GEMM (448 tiles, no holes)
  k_gemm_out<<<448, 256, 0, stream>>>(enc, bto0, bto1, out0, out1);
}

// Round 12
// 186.758 us; speedup vs baseline: 1.0887x; 1.0116x over previous
//
#include <hip/hip_runtime.h>
#include <hip/hip_bf16.h>

typedef __attribute__((ext_vector_type(8))) short bf16x8;
typedef __attribute__((ext_vector_type(4))) float f32x4;
typedef __attribute__((ext_vector_type(4))) unsigned short u16x4;
typedef unsigned short US;

__device__ __forceinline__ f32x4 mfma16(bf16x8 a, bf16x8 b, f32x4 c) {
  return __builtin_amdgcn_mfma_f32_16x16x32_bf16(a, b, c, 0, 0, 0);
}

__device__ __forceinline__ US f2bf(float f) {
  union { float f; unsigned u; } x; x.f = f;
  unsigned r = x.u + 0x7fffu + ((x.u >> 16) & 1u);
  return (US)(r >> 16);
}

// async global->LDS, 16B per lane; LDS dest = wave-uniform base + lane*16
__device__ __forceinline__ void gld16(const US* gp, US* lp) {
  __builtin_amdgcn_global_load_lds(
      (const __attribute__((address_space(1))) unsigned*)gp,
      (__attribute__((address_space(3))) unsigned*)lp, 16, 0, 0);
}

// RoPE column permutation: logical h (0..127) -> physical p; partner h+128 -> p+16.
__device__ __forceinline__ int permq(int h) {  // h in [0,128)
  return ((h >> 5) << 6) + (h & 15) + (((h >> 4) & 1) << 5);
}

// row remap fusing the time-concat: mode1: r=b*768+s -> b*1024+s ; mode2: r=b*256+s -> b*1024+768+s
__device__ __forceinline__ int map_row(int r, int mode) {
  if (mode == 1) { int b = r / 768; return b * 1024 + (r - b * 768); }
  if (mode == 2) { int b = r >> 8; return b * 1024 + 768 + (r & 255); }
  return r;
}

// ------- fused prep: casts + qkv weight transpose-packs + sin/cos table -------
// (wo0/wo1 packs live in the k_attn launch to overlap with attention)
__global__ __launch_bounds__(256)
void k_prep(const float* __restrict__ x0, const float* __restrict__ x1,
            US* __restrict__ x0b, US* __restrict__ x1b,
            const float* __restrict__ wq0, const float* __restrict__ wkv0,
            const float* __restrict__ wq1, const float* __restrict__ wkv1,
            US* __restrict__ btq0, US* __restrict__ btkv0,
            US* __restrict__ btq1, US* __restrict__ btkv1,
            const int* __restrict__ pos, float2* __restrict__ sct) {
  const int bid = blockIdx.x;
  const int tid = threadIdx.x;
  if (bid >= 14848) {  // sin/cos table: 2048 blocks, 512K entries
    int idx = (bid - 14848) * 256 + tid;
    int bt = idx >> 7, j = idx & 127;
    // inv_ts = 10000^(-j/128) via HW-rate exp; sincos intrinsics.
    float inv_ts = __expf(-0.0719557841f * (float)j);
    float r = (float)pos[bt] * inv_ts;
    float s, co;
    __sincosf(r, &s, &co);
    sct[idx] = make_float2(s, co);
    return;
  }
  if (bid < 7168) {  // bf16 casts
    const float* src; US* dst; int i;
    if (bid < 6144) { src = x0; dst = x0b; i = bid * 256 + tid; }
    else            { src = x1; dst = x1b; i = (bid - 6144) * 256 + tid; }
    f32x4 v = *reinterpret_cast<const f32x4*>(src + (size_t)i * 4);
    u16x4 o;
    o[0] = f2bf(v[0]); o[1] = f2bf(v[1]); o[2] = f2bf(v[2]); o[3] = f2bf(v[3]);
    *reinterpret_cast<u16x4*>(dst + (size_t)i * 4) = o;
    return;
  }
  __shared__ float tile[32][33];
  const float* src; US* dst; int R, C, CX, local; long sbs, dbs; bool pq = false;
  if (bid < 11264)      { local = bid - 7168;  src = wq0;  dst = btq0;  R = 2048; C = 256; CX = 8; sbs = 2048L * 256; dbs = 256L * 2048; pq = true; }
  else if (bid < 12288) { local = bid - 11264; src = wkv0; dst = btkv0; R = 2048; C = 256; CX = 8; sbs = 2048L * 256; dbs = 256L * 2048; }
  else if (bid < 14336) { local = bid - 12288; src = wq1;  dst = btq1;  R = 1024; C = 256; CX = 8; sbs = 1024L * 256; dbs = 256L * 1024; pq = true; }
  else                  { local = bid - 14336; src = wkv1; dst = btkv1; R = 1024; C = 256; CX = 8; sbs = 1024L * 256; dbs = 256L * 1024; }
  const int RY = R >> 5;
  const int cx = local % CX;
  const int rest = local / CX;
  const int ry = rest % RY;
  const int z = rest / RY;
  const int c0 = cx * 32, r0 = ry * 32;
  const int tx = tid & 31, ty = tid >> 5;
  src += (long)z * sbs;
  dst += (long)z * dbs;
#pragma unroll
  for (int i = 0; i < 4; ++i)
    tile[ty + 8 * i][tx] = src[(size_t)(r0 + ty + 8 * i) * C + c0 + tx];
  __syncthreads();
#pragma unroll
  for (int i = 0; i < 4; ++i) {
    int h = c0 + ty + 8 * i;
    int ph = pq ? ((h < 128) ? permq(h) : permq(h - 128) + 16) : h;
    dst[(size_t)ph * R + r0 + tx] = f2bf(tile[tx][ty + 8 * i]);
  }
}

// ------- merged QKV projection GEMM: heavy (K=2048) tiles dispatch FIRST, -------
// light (K=1024) tiles LAST -> the ragged 3rd residency-round is half-cost (LPT).
// Per-group bijective XCD striping keeps the L2 locality.
__global__ __launch_bounds__(256, 2)
void k_gemm_qkv(const US* __restrict__ x0b, const US* __restrict__ x1b,
                const US* __restrict__ btq0, const US* __restrict__ btq1,
                US* __restrict__ q_bf, float* __restrict__ Ckv,
                const float2* __restrict__ sct) {
  const int bid = blockIdx.x;
  const US* A; const US* BT; int K, cmap, by, bx;
  if (bid < 480) {  // heavy: seg0, 480 = 8*60 bijective XCD stripe
    int id = (bid & 7) * 60 + (bid >> 3);
    A = x0b; BT = btq0; K = 2048; cmap = 1; by = id / 20; bx = id % 20;
  } else {          // light: seg1, 160 = 8*20 bijective XCD stripe
    int l = bid - 480;
    int id = (l & 7) * 20 + (l >> 3);
    A = x1b; BT = btq1; K = 1024; cmap = 2; by = id / 20; bx = id % 20;
  }

  __shared__ __align__(16) US lA[2][128 * 32];
  __shared__ __align__(16) US lB[2][128 * 32];
  const int tid = threadIdx.x;
  const int lane = tid & 63;
  const int wid = tid >> 6;
  const int wm = wid >> 1, wn = wid & 1;
  const int m0 = by * 128, n0 = bx * 128;
  const int g = lane >> 4, c = lane & 15;
  const int lrow = lane >> 2, lcol = (lane & 3) * 8;
  const size_t ga0 = (size_t)(m0 + wid * 16 + lrow) * K + lcol;
  const size_t ga1 = (size_t)(m0 + 64 + wid * 16 + lrow) * K + lcol;
  const size_t gb0 = (size_t)(n0 + wid * 16 + lrow) * K + lcol;
  const size_t gb1 = (size_t)(n0 + 64 + wid * 16 + lrow) * K + lcol;

  auto stage = [&](int bi, int k0) {
    gld16(A + ga0 + k0, &lA[bi][(wid * 16) * 32]);
    gld16(A + ga1 + k0, &lA[bi][(64 + wid * 16) * 32]);
    gld16(BT + gb0 + k0, &lB[bi][(wid * 16) * 32]);
    gld16(BT + gb1 + k0, &lB[bi][(64 + wid * 16) * 32]);
  };

  f32x4 acc[4][4];
#pragma unroll
  for (int i = 0; i < 4; ++i)
#pragma unroll
    for (int j = 0; j < 4; ++j) acc[i][j] = f32x4{0.f, 0.f, 0.f, 0.f};

  const int nt = K >> 5;
  stage(0, 0);
  __syncthreads();
  for (int t = 0; t < nt; ++t) {
    const int bi = t & 1;
    if (t + 1 < nt) stage(bi ^ 1, (t + 1) * 32);
    bf16x8 af[4], bfr[4];
#pragma unroll
    for (int i = 0; i < 4; ++i) {
      af[i] = *reinterpret_cast<const bf16x8*>(&lA[bi][(wm * 64 + i * 16 + c) * 32 + g * 8]);
      bfr[i] = *reinterpret_cast<const bf16x8*>(&lB[bi][(wn * 64 + i * 16 + c) * 32 + g * 8]);
    }
#pragma unroll
    for (int i = 0; i < 4; ++i)
#pragma unroll
      for (int j = 0; j < 4; ++j)
        acc[i][j] = mfma16(af[i], bfr[j], acc[i][j]);
    __syncthreads();  // drains vmcnt(0): prefetch landed; buf[bi] reads done
  }

  const int colb = n0 + wn * 64;
  if (colb < 2048) {
    // q path: RoPE + scale -> bf16 (permuted layout; pairs are (j0,j1),(j2,j3))
    const int n = colb >> 8;
    const int base64 = colb & 255;
    const int h0 = (base64 >> 6) * 32 + c;
    const float scale = 0.0625f;
#pragma unroll
    for (int i = 0; i < 4; ++i) {
#pragma unroll
      for (int r = 0; r < 4; ++r) {
        const int orow = map_row(m0 + wm * 64 + i * 16 + 4 * g + r, cmap);
        const float2 sc0 = sct[orow * 128 + h0];
        const float2 sc1 = sct[orow * 128 + h0 + 16];
        US* qp = q_bf + ((size_t)orow * 8 + n) * 256 + base64 + c;
        const float q1 = acc[i][0][r], q2 = acc[i][1][r];
        const float q3 = acc[i][2][r], q4 = acc[i][3][r];
        qp[0]  = f2bf(scale * (q1 * sc0.y - q2 * sc0.x));
        qp[16] = f2bf(scale * (q2 * sc0.y + q1 * sc0.x));
        qp[32] = f2bf(scale * (q3 * sc1.y - q4 * sc1.x));
        qp[48] = f2bf(scale * (q4 * sc1.y + q3 * sc1.x));
      }
    }
  } else {
    const int nb = colb - 2048 + c;
#pragma unroll
    for (int i = 0; i < 4; ++i) {
#pragma unroll
      for (int r = 0; r < 4; ++r) {
        const int orow = map_row(m0 + wm * 64 + i * 16 + 4 * g + r, cmap);
        float* cp = Ckv + (size_t)orow * 512 + nb;
#pragma unroll
        for (int j = 0; j < 4; ++j) cp[j * 16] = acc[i][j][r];
      }
    }
  }
}

// ------- compact output GEMM: 448 tiles (384 out0 + 64 out1), XCD-swizzled -------
__global__ __launch_bounds__(256, 2)
void k_gemm_out(const US* __restrict__ A, const US* __restrict__ BT0, const US* __restrict__ BT1,
                float* __restrict__ C0, float* __restrict__ C1) {
  const int bid = blockIdx.x;
  int id = (bid & 7) * 56 + (bid >> 3);   // bijective XCD swizzle (448 = 8*56)
  const US* BT; float* Cb; int amap, mt, ntile, Nst;
  if (id < 384) { amap = 1; mt = id / 16; ntile = id % 16; BT = BT0; Cb = C0; Nst = 2048; }
  else { id -= 384; amap = 2; mt = id / 8; ntile = id % 8; BT = BT1; Cb = C1; Nst = 1024; }
  const int m0 = mt * 128, n0 = ntile * 128;
  const int K = 2048;
  __shared__ __align__(16) US lA[2][128 * 32];
  __shared__ __align__(16) US lB[2][128 * 32];
  const int tid = threadIdx.x;
  const int lane = tid & 63;
  const int wid = tid >> 6;
  const int wm = wid >> 1, wn = wid & 1;
  const int g = lane >> 4, c = lane & 15;
  const int lrow = lane >> 2, lcol = (lane & 3) * 8;
  const size_t ga0 = (size_t)map_row(m0 + wid * 16 + lrow, amap) * K + lcol;
  const size_t ga1 = (size_t)map_row(m0 + 64 + wid * 16 + lrow, amap) * K + lcol;
  const size_t gb0 = (size_t)(n0 + wid * 16 + lrow) * K + lcol;
  const size_t gb1 = (size_t)(n0 + 64 + wid * 16 + lrow) * K + lcol;

  auto stage = [&](int bi, int k0) {
    gld16(A + ga0 + k0, &lA[bi][(wid * 16) * 32]);
    gld16(A + ga1 + k0, &lA[bi][(64 + wid * 16) * 32]);
    gld16(BT + gb0 + k0, &lB[bi][(wid * 16) * 32]);
    gld16(BT + gb1 + k0, &lB[bi][(64 + wid * 16) * 32]);
  };

  f32x4 acc[4][4];
#pragma unroll
  for (int i = 0; i < 4; ++i)
#pragma unroll
    for (int j = 0; j < 4; ++j) acc[i][j] = f32x4{0.f, 0.f, 0.f, 0.f};

  const int nt = K >> 5;
  stage(0, 0);
  __syncthreads();
  for (int t = 0; t < nt; ++t) {
    const int bi = t & 1;
    if (t + 1 < nt) stage(bi ^ 1, (t + 1) * 32);
    bf16x8 af[4], bfr[4];
#pragma unroll
    for (int i = 0; i < 4; ++i) {
      af[i] = *reinterpret_cast<const bf16x8*>(&lA[bi][(wm * 64 + i * 16 + c) * 32 + g * 8]);
      bfr[i] = *reinterpret_cast<const bf16x8*>(&lB[bi][(wn * 64 + i * 16 + c) * 32 + g * 8]);
    }
#pragma unroll
    for (int i = 0; i < 4; ++i)
#pragma unroll
      for (int j = 0; j < 4; ++j)
        acc[i][j] = mfma16(af[i], bfr[j], acc[i][j]);
    __syncthreads();
  }

  const int col = n0 + wn * 64 + c;
#pragma unroll
  for (int i = 0; i < 4; ++i) {
#pragma unroll
    for (int r = 0; r < 4; ++r) {
      const int orow = m0 + wm * 64 + i * 16 + 4 * g + r;  // compact per-segment row
      float* cp = Cb + (size_t)orow * Nst + col;
#pragma unroll
      for (int j = 0; j < 4; ++j) cp[j * 16] = acc[i][j][r];
    }
  }
}

// ------- merged post-KV: V transpose (+v_out) and k-RoPE (+k_out) in one launch -------
__global__ __launch_bounds__(256)
void k_postkv(const float* __restrict__ kv_raw, const float2* __restrict__ sct,
              US* __restrict__ k_bf, float* __restrict__ k_out,
              float* __restrict__ v_out, US* __restrict__ vt) {
  const int bid = blockIdx.x;
  const int tid = threadIdx.x;
  if (bid >= 1024) {  // k-RoPE: 2048 blocks, 2 bt-rows each
    const int bt = (bid - 1024) * 2 + (tid >> 7);
    const int j = tid & 127;
    const size_t ko = (size_t)bt * 512;
    const float x1 = kv_raw[ko + j], x2 = kv_raw[ko + j + 128];
    const float2 sc = sct[bt * 128 + j];
    const float o1 = x1 * sc.y - x2 * sc.x, o2 = x2 * sc.y + x1 * sc.x;
    const size_t kd = (size_t)bt * 256;
    const int p = permq(j);
    k_bf[kd + p] = f2bf(o1);
    k_bf[kd + p + 16] = f2bf(o2);
    k_out[kd + j] = o1;
    k_out[kd + j + 128] = o2;
    return;
  }
  __shared__ float tile[32][33];
  const int t0 = (bid & 31) * 32, h0 = ((bid >> 5) & 7) * 32, b = bid >> 8;
  const int tx = tid & 31, ty = tid >> 5;
#pragma unroll
  for (int i = 0; i < 4; ++i) {
    int t = t0 + ty + 8 * i;
    float v = kv_raw[(size_t)(b * 1024 + t) * 512 + 256 + h0 + tx];
    tile[ty + 8 * i][tx] = v;
    v_out[(size_t)(b * 1024 + t) * 256 + h0 + tx] = v;
  }
  __syncthreads();
#pragma unroll
  for (int i = 0; i < 4; ++i) {
    int h = h0 + ty + 8 * i;
    vt[(size_t)(b * 256 + h) * 1024 + t0 + tx] = f2bf(tile[tx][ty + 8 * i]);
  }
}

// ------- flash attention (R8 structure) + overlapped wo weight-packing -------
__global__ __launch_bounds__(256, 2)
void k_attn(const US* __restrict__ qb, const US* __restrict__ kb,
            const US* __restrict__ vt, US* __restrict__ enc,
            const float* __restrict__ wo0, const float* __restrict__ wo1,
            US* __restrict__ bto0, US* __restrict__ bto1) {
  __shared__ __align__(16) US lK[2][32 * 256];   // 16KB x2
  __shared__ __align__(16) US lV[2][256 * 32];   // 16KB x2
  const int id = blockIdx.x;
  const int tid = threadIdx.x;

  if (id >= 512) {  // ---- wo pack path ----
    int local = id - 512;
    const float* src; US* dst; int C, CX;
    if (local < 4096) { src = wo0; dst = bto0; C = 2048; CX = 64; }
    else { local -= 4096; src = wo1; dst = bto1; C = 1024; CX = 32; }
    const int cx = local % CX, ry = local / CX;
    const int c0p = cx * 32, r0p = ry * 32;
    const int tx = tid & 31, ty = tid >> 5;
    float* tileF = (float*)&lK[0][0];  // 32x33 f32 aliases attn LDS
#pragma unroll
    for (int i = 0; i < 4; ++i)
      tileF[(ty + 8 * i) * 33 + tx] = src[(size_t)(r0p + ty + 8 * i) * C + c0p + tx];
    __syncthreads();
#pragma unroll
    for (int i = 0; i < 4; ++i)
      dst[(size_t)(c0p + ty + 8 * i) * 2048 + r0p + tx] = f2bf(tileF[tx * 33 + ty + 8 * i]);
    return;
  }

  // ---- attention path ----
  const int r0_ = (id < 256) ? id : 767 - id;    // work rank, descending length
  const int qt = 63 - (r0_ >> 3);
  const int hg = (r0_ >> 2) & 1;
  const int b = r0_ & 3;
  const int wid = tid >> 6;
  const int lane = tid & 63;
  const int g = lane >> 4, c = lane & 15;
  const int qbase = qt * 16;
  const int n = hg * 4 + wid;

  const US* kbB = kb + (size_t)b * 262144;
  const US* vtB = vt + (size_t)b * 262144;

  bf16x8 qf[8];
  {
    const US* qp = qb + ((size_t)((b * 1024 + qbase + c) * 8 + n)) * 256 + 8 * g;
#pragma unroll
    for (int ch = 0; ch < 8; ++ch)
      qf[ch] = *reinterpret_cast<const bf16x8*>(qp + ch * 32);
  }

  auto stage = [&](int bi, int c0) {
#pragma unroll
    for (int j = 0; j < 4; ++j) {
      const int rk = wid * 8 + j * 2 + (lane >> 5);
      const int sk = lane & 31;
      gld16(kbB + (size_t)(c0 + rk) * 256 + (sk ^ (rk & 7)) * 8,
            &lK[bi][(wid * 8 + j * 2) * 256]);
      const int rv = wid * 64 + j * 16 + (lane >> 2);
      const int sv = lane & 3;
      gld16(vtB + (size_t)rv * 1024 + c0 + (sv ^ ((rv >> 1) & 3)) * 8,
            &lV[bi][(wid * 64 + j * 16) * 32]);
    }
  };

  f32x4 acc[16];
#pragma unroll
  for (int i = 0; i < 16; ++i) acc[i] = f32x4{0.f, 0.f, 0.f, 0.f};
  float m_run = -3.0e38f, l_run = 0.f;

  const int nC = qbase / 32 + 1;
  stage(0, 0);
  __syncthreads();

  for (int i = 0; i < nC; ++i) {
    const int c0 = 32 * i;
    const int bi = i & 1;
    if (i + 1 < nC) stage(bi ^ 1, c0 + 32);

    const bool hb = (c0 + 16 <= qbase);
    f32x4 sA = {0.f, 0.f, 0.f, 0.f}, sB = {0.f, 0.f, 0.f, 0.f};
    __builtin_amdgcn_s_setprio(1);
#pragma unroll
    for (int ch = 0; ch < 8; ++ch) {
      const int slot = (((ch * 4 + g) ^ (c & 7)) * 8);
      sA = mfma16(*reinterpret_cast<const bf16x8*>(&lK[bi][c * 256 + slot]), qf[ch], sA);
    }
    if (hb) {
#pragma unroll
      for (int ch = 0; ch < 8; ++ch) {
        const int slot = (((ch * 4 + g) ^ (c & 7)) * 8);  // (c+16)&7 == c&7
        sB = mfma16(*reinterpret_cast<const bf16x8*>(&lK[bi][(c + 16) * 256 + slot]), qf[ch], sB);
      }
    }
    __builtin_amdgcn_s_setprio(0);
    if (c0 == qbase) {
#pragma unroll
      for (int r = 0; r < 4; ++r)
        if (4 * g + r > c) sA[r] = -3.0e38f;
    }
    if (hb && (c0 + 16 == qbase)) {
#pragma unroll
      for (int r = 0; r < 4; ++r)
        if (4 * g + r > c) sB[r] = -3.0e38f;
    }
    float tm = fmaxf(fmaxf(sA[0], sA[1]), fmaxf(sA[2], sA[3]));
    if (hb) tm = fmaxf(tm, fmaxf(fmaxf(sB[0], sB[1]), fmaxf(sB[2], sB[3])));
    tm = fmaxf(tm, __shfl_xor(tm, 16));
    tm = fmaxf(tm, __shfl_xor(tm, 32));
    // defer-max: only rescale when the running max actually grows past THR
    if (!__all(tm - m_run <= 8.0f)) {
      const float m_new = fmaxf(m_run, tm);
      const float alpha = __expf(m_run - m_new);
      float aacc[4];
#pragma unroll
      for (int r = 0; r < 4; ++r) aacc[r] = __shfl(alpha, 4 * g + r);
#pragma unroll
      for (int ht = 0; ht < 16; ++ht) {
        acc[ht][0] *= aacc[0]; acc[ht][1] *= aacc[1];
        acc[ht][2] *= aacc[2]; acc[ht][3] *= aacc[3];
      }
      l_run *= alpha;
      m_run = m_new;
    }
    float pA[4], pB[4];
    float ls = 0.f;
#pragma unroll
    for (int r = 0; r < 4; ++r) { pA[r] = __expf(sA[r] - m_run); ls += pA[r]; }
#pragma unroll
    for (int r = 0; r < 4; ++r) { pB[r] = hb ? __expf(sB[r] - m_run) : 0.f; ls += pB[r]; }
    ls += __shfl_xor(ls, 16);
    ls += __shfl_xor(ls, 32);
    l_run += ls;

    // --- paf butterfly: pack P to bf16 pairs, then 2-stage 4-lane-group transpose ---
    unsigned w0, w1, w2, w3;
    asm("v_cvt_pk_bf16_f32 %0, %1, %2" : "=v"(w0) : "v"(pA[0]), "v"(pA[1]));
    asm("v_cvt_pk_bf16_f32 %0, %1, %2" : "=v"(w1) : "v"(pA[2]), "v"(pA[3]));
    asm("v_cvt_pk_bf16_f32 %0, %1, %2" : "=v"(w2) : "v"(pB[0]), "v"(pB[1]));
    asm("v_cvt_pk_bf16_f32 %0, %1, %2" : "=v"(w3) : "v"(pB[2]), "v"(pB[3]));
    const bool bb1 = ((g >> 1) & 1) != 0, bb0 = (g & 1) != 0;
    unsigned ownA = bb1 ? w2 : w0, ownB = bb1 ? w3 : w1;
    unsigned sndA = bb1 ? w0 : w2, sndB = bb1 ? w1 : w3;
    unsigned rcvA = (unsigned)__shfl_xor((int)sndA, 32);
    unsigned rcvB = (unsigned)__shfl_xor((int)sndB, 32);
    unsigned kA = (bb0 == bb1) ? ownA : rcvA, kB = (bb0 == bb1) ? ownB : rcvB;
    unsigned s2A = (bb0 == bb1) ? rcvA : ownA, s2B = (bb0 == bb1) ? rcvB : ownB;
    unsigned gA = (unsigned)__shfl_xor((int)s2A, 16);
    unsigned gB = (unsigned)__shfl_xor((int)s2B, 16);
    union { unsigned u[4]; bf16x8 v; } pu;
    pu.u[0] = bb0 ? gA : kA; pu.u[1] = bb0 ? gB : kB;
    pu.u[2] = bb0 ? kA : gA; pu.u[3] = bb0 ? kB : gB;
    const bf16x8 paf = pu.v;

    __builtin_amdgcn_s_setprio(1);
#pragma unroll
    for (int ht = 0; ht < 16; ++ht) {
      const int h = ht * 16 + c;
      const int slot = (g ^ ((c >> 1) & 3)) * 8;
      bf16x8 vf = *reinterpret_cast<const bf16x8*>(&lV[bi][h * 32 + slot]);
      acc[ht] = mfma16(paf, vf, acc[ht]);
    }
    __builtin_amdgcn_s_setprio(0);
    __syncthreads();  // buf[bi] reads done; staging of buf[bi^1] drained
  }

  const float inv = 1.0f / l_run;
  float ia[4];
#pragma unroll
  for (int r = 0; r < 4; ++r) ia[r] = __shfl(inv, 4 * g + r);
#pragma unroll
  for (int ht = 0; ht < 16; ++ht) {
#pragma unroll
    for (int r = 0; r < 4; ++r) {
      size_t o = ((size_t)((b * 1024 + qbase + 4 * g + r) * 8 + n)) * 256 + ht * 16 + c;
      enc[o] = f2bf(acc[ht][r] * ia[r]);
    }
  }
}

extern "C" void kernel_launch(void* const* d_in, const int* in_sizes, int n_in,
                              void* d_out, int out_size, void* d_ws, size_t ws_size,
                              hipStream_t stream) {
  const float* x0 = (const float*)d_in[0];
  const float* x1 = (const float*)d_in[1];
  const float* wq0 = (const float*)d_in[2];
  const float* wkv0 = (const float*)d_in[3];
  const float* wo0 = (const float*)d_in[4];
  const float* wq1 = (const float*)d_in[5];
  const float* wkv1 = (const float*)d_in[6];
  const float* wo1 = (const float*)d_in[7];
  const int* pos = (const int*)d_in[8];
  float* out = (float*)d_out;

  float* out0 = out;                    // 4*768*2048
  float* out1 = out + 6291456;          // 4*256*1024
  float* k_out = out + 7340032;         // 4*1024*256
  float* v_out = out + 8388608;         // 4*1024*256

  char* ws = (char*)d_ws;
  size_t off = 0;
  auto alloc = [&](size_t bytes) {
    char* p = ws + off;
    off += (bytes + 255) & ~(size_t)255;
    return p;
  };
  US* x0b   = (US*)alloc(6291456ull * 2);
  US* x1b   = (US*)alloc(1048576ull * 2);
  US* btq0  = (US*)alloc(2048ull * 2048 * 2);   // btq0+btkv0 contiguous: [2560][2048]
  US* btkv0 = (US*)alloc(512ull * 2048 * 2);
  US* btq1  = (US*)alloc(2048ull * 1024 * 2);   // btq1+btkv1 contiguous: [2560][1024]
  US* btkv1 = (US*)alloc(512ull * 1024 * 2);
  US* bto0  = (US*)alloc(2048ull * 2048 * 2);
  US* bto1  = (US*)alloc(1024ull * 2048 * 2);
  float* kv_raw = (float*)alloc(2097152ull * 4);
  US* q_bf = (US*)alloc(8388608ull * 2);
  US* k_bf = (US*)alloc(1048576ull * 2);
  US* vt   = (US*)alloc(1048576ull * 2 + 256);
  US* enc  = (US*)alloc(8388608ull * 2);
  float2* sct = (float2*)alloc(524288ull * 8);
  (void)btkv0; (void)btkv1;

  // phase 1: fused casts + qkv weight packs + sin/cos table
  k_prep<<<16896, 256, 0, stream>>>(x0, x1, x0b, x1b, wq0, wkv0, wq1, wkv1,
                                    btq0, btkv0, btq1, btkv1, pos, sct);

  // phase 2: merged QKV projection GEMMs (heavy-first LPT dispatch order)
  k_gemm_qkv<<<640, 256, 0, stream>>>(x0b, x1b, btq0, btq1, q_bf, kv_raw, sct);

  // phase 3: merged k-RoPE + V transpose (emit k, v fp32 outputs)
  k_postkv<<<3072, 256, 0, stream>>>(kv_raw, sct, k_bf, k_out, v_out, vt);

  // phase 4: causal flash attention + overlapped wo0/wo1 weight packs
  k_attn<<<6656, 256, 0, stream>>>(q_bf, k_bf, vt, enc, wo0, wo1, bto0, bto1);

  // phase 5: compact fused output GEMM (448 tiles, no holes)
  k_gemm_out<<<448, 256, 0, stream>>>(enc, bto0, bto1, out0, out1);
}

// Round 13
// 182.887 us; speedup vs baseline: 1.1117x; 1.0212x over previous
//
#include <hip/hip_runtime.h>
#include <hip/hip_bf16.h>

typedef __attribute__((ext_vector_type(8))) short bf16x8;
typedef __attribute__((ext_vector_type(4))) float f32x4;
typedef __attribute__((ext_vector_type(4))) unsigned short u16x4;
typedef unsigned short US;

__device__ __forceinline__ f32x4 mfma16(bf16x8 a, bf16x8 b, f32x4 c) {
  return __builtin_amdgcn_mfma_f32_16x16x32_bf16(a, b, c, 0, 0, 0);
}

__device__ __forceinline__ US f2bf(float f) {
  union { float f; unsigned u; } x; x.f = f;
  unsigned r = x.u + 0x7fffu + ((x.u >> 16) & 1u);
  return (US)(r >> 16);
}

// async global->LDS, 16B per lane; LDS dest = wave-uniform base + lane*16
__device__ __forceinline__ void gld16(const US* gp, US* lp) {
  __builtin_amdgcn_global_load_lds(
      (const __attribute__((address_space(1))) unsigned*)gp,
      (__attribute__((address_space(3))) unsigned*)lp, 16, 0, 0);
}

// RoPE column permutation: logical h (0..127) -> physical p; partner h+128 -> p+16.
__device__ __forceinline__ int permq(int h) {  // h in [0,128)
  return ((h >> 5) << 6) + (h & 15) + (((h >> 4) & 1) << 5);
}

// row remap fusing the time-concat: mode1: r=b*768+s -> b*1024+s ; mode2: r=b*256+s -> b*1024+768+s
__device__ __forceinline__ int map_row(int r, int mode) {
  if (mode == 1) { int b = r / 768; return b * 1024 + (r - b * 768); }
  if (mode == 2) { int b = r >> 8; return b * 1024 + 768 + (r & 255); }
  return r;
}

// ------- fused prep: casts + qkv weight transpose-packs + sin/cos table -------
// q-weights AND k-weights (wkv z==0) get the RoPE column permutation so the
// GEMM epilogue can rope both q and k thread-locally.
__global__ __launch_bounds__(256)
void k_prep(const float* __restrict__ x0, const float* __restrict__ x1,
            US* __restrict__ x0b, US* __restrict__ x1b,
            const float* __restrict__ wq0, const float* __restrict__ wkv0,
            const float* __restrict__ wq1, const float* __restrict__ wkv1,
            US* __restrict__ btq0, US* __restrict__ btkv0,
            US* __restrict__ btq1, US* __restrict__ btkv1,
            const int* __restrict__ pos, float2* __restrict__ sct) {
  const int bid = blockIdx.x;
  const int tid = threadIdx.x;
  if (bid >= 14848) {  // sin/cos table: 2048 blocks, 512K entries
    int idx = (bid - 14848) * 256 + tid;
    int bt = idx >> 7, j = idx & 127;
    float inv_ts = __expf(-0.0719557841f * (float)j);
    float r = (float)pos[bt] * inv_ts;
    float s, co;
    __sincosf(r, &s, &co);
    sct[idx] = make_float2(s, co);
    return;
  }
  if (bid < 7168) {  // bf16 casts
    const float* src; US* dst; int i;
    if (bid < 6144) { src = x0; dst = x0b; i = bid * 256 + tid; }
    else            { src = x1; dst = x1b; i = (bid - 6144) * 256 + tid; }
    f32x4 v = *reinterpret_cast<const f32x4*>(src + (size_t)i * 4);
    u16x4 o;
    o[0] = f2bf(v[0]); o[1] = f2bf(v[1]); o[2] = f2bf(v[2]); o[3] = f2bf(v[3]);
    *reinterpret_cast<u16x4*>(dst + (size_t)i * 4) = o;
    return;
  }
  __shared__ float tile[32][33];
  const float* src; US* dst; int R, C, CX, local; long sbs, dbs;
  bool pq = false, pkv = false;
  if (bid < 11264)      { local = bid - 7168;  src = wq0;  dst = btq0;  R = 2048; C = 256; CX = 8; sbs = 2048L * 256; dbs = 256L * 2048; pq = true; }
  else if (bid < 12288) { local = bid - 11264; src = wkv0; dst = btkv0; R = 2048; C = 256; CX = 8; sbs = 2048L * 256; dbs = 256L * 2048; pkv = true; }
  else if (bid < 14336) { local = bid - 12288; src = wq1;  dst = btq1;  R = 1024; C = 256; CX = 8; sbs = 1024L * 256; dbs = 256L * 1024; pq = true; }
  else                  { local = bid - 14336; src = wkv1; dst = btkv1; R = 1024; C = 256; CX = 8; sbs = 1024L * 256; dbs = 256L * 1024; pkv = true; }
  const int RY = R >> 5;
  const int cx = local % CX;
  const int rest = local / CX;
  const int ry = rest % RY;
  const int z = rest / RY;
  const int c0 = cx * 32, r0 = ry * 32;
  const int tx = tid & 31, ty = tid >> 5;
  src += (long)z * sbs;
  dst += (long)z * dbs;
  const bool doperm = pq || (pkv && z == 0);   // k-weights (z==0) permuted like q
#pragma unroll
  for (int i = 0; i < 4; ++i)
    tile[ty + 8 * i][tx] = src[(size_t)(r0 + ty + 8 * i) * C + c0 + tx];
  __syncthreads();
#pragma unroll
  for (int i = 0; i < 4; ++i) {
    int h = c0 + ty + 8 * i;
    int ph = doperm ? ((h < 128) ? permq(h) : permq(h - 128) + 16) : h;
    dst[(size_t)ph * R + r0 + tx] = f2bf(tile[tx][ty + 8 * i]);
  }
}

// ------- merged QKV projection GEMM, fully-fused epilogue -------
// q cols  (<2048):       RoPE + scale -> q_bf (permuted bf16)
// k cols  (2048..2303):  RoPE -> k_bf (permuted bf16) + k_out (logical fp32)
// v cols  (2304..2559):  v_out (fp32, coalesced) + vt (bf16 [b][h][t], 8B packed)
// Heavy tiles (K=2048) dispatch first, light (K=1024) last (LPT); per-group
// bijective XCD striping. kv_raw scratch and the postkv kernel are eliminated.
__global__ __launch_bounds__(256, 2)
void k_gemm_qkv(const US* __restrict__ x0b, const US* __restrict__ x1b,
                const US* __restrict__ btq0, const US* __restrict__ btq1,
                US* __restrict__ q_bf, US* __restrict__ k_bf,
                float* __restrict__ k_out, float* __restrict__ v_out,
                US* __restrict__ vt, const float2* __restrict__ sct) {
  const int bid = blockIdx.x;
  const US* A; const US* BT; int K, cmap, by, bx;
  if (bid < 480) {  // heavy: seg0, 480 = 8*60 bijective XCD stripe
    int id = (bid & 7) * 60 + (bid >> 3);
    A = x0b; BT = btq0; K = 2048; cmap = 1; by = id / 20; bx = id % 20;
  } else {          // light: seg1, 160 = 8*20 bijective XCD stripe
    int l = bid - 480;
    int id = (l & 7) * 20 + (l >> 3);
    A = x1b; BT = btq1; K = 1024; cmap = 2; by = id / 20; bx = id % 20;
  }

  __shared__ __align__(16) US lA[2][128 * 32];
  __shared__ __align__(16) US lB[2][128 * 32];
  const int tid = threadIdx.x;
  const int lane = tid & 63;
  const int wid = tid >> 6;
  const int wm = wid >> 1, wn = wid & 1;
  const int m0 = by * 128, n0 = bx * 128;
  const int g = lane >> 4, c = lane & 15;
  const int lrow = lane >> 2, lcol = (lane & 3) * 8;
  const size_t ga0 = (size_t)(m0 + wid * 16 + lrow) * K + lcol;
  const size_t ga1 = (size_t)(m0 + 64 + wid * 16 + lrow) * K + lcol;
  const size_t gb0 = (size_t)(n0 + wid * 16 + lrow) * K + lcol;
  const size_t gb1 = (size_t)(n0 + 64 + wid * 16 + lrow) * K + lcol;

  auto stage = [&](int bi, int k0) {
    gld16(A + ga0 + k0, &lA[bi][(wid * 16) * 32]);
    gld16(A + ga1 + k0, &lA[bi][(64 + wid * 16) * 32]);
    gld16(BT + gb0 + k0, &lB[bi][(wid * 16) * 32]);
    gld16(BT + gb1 + k0, &lB[bi][(64 + wid * 16) * 32]);
  };

  f32x4 acc[4][4];
#pragma unroll
  for (int i = 0; i < 4; ++i)
#pragma unroll
    for (int j = 0; j < 4; ++j) acc[i][j] = f32x4{0.f, 0.f, 0.f, 0.f};

  const int nt = K >> 5;
  stage(0, 0);
  __syncthreads();
  for (int t = 0; t < nt; ++t) {
    const int bi = t & 1;
    if (t + 1 < nt) stage(bi ^ 1, (t + 1) * 32);
    bf16x8 af[4], bfr[4];
#pragma unroll
    for (int i = 0; i < 4; ++i) {
      af[i] = *reinterpret_cast<const bf16x8*>(&lA[bi][(wm * 64 + i * 16 + c) * 32 + g * 8]);
      bfr[i] = *reinterpret_cast<const bf16x8*>(&lB[bi][(wn * 64 + i * 16 + c) * 32 + g * 8]);
    }
#pragma unroll
    for (int i = 0; i < 4; ++i)
#pragma unroll
      for (int j = 0; j < 4; ++j)
        acc[i][j] = mfma16(af[i], bfr[j], acc[i][j]);
    __syncthreads();  // drains vmcnt(0): prefetch landed; buf[bi] reads done
  }

  const int colb = n0 + wn * 64;
  if (colb < 2048) {
    // q path: RoPE + scale -> bf16 (permuted layout; pairs (0,16) and (32,48))
    const int n = colb >> 8;
    const int base64 = colb & 255;
    const int h0 = (base64 >> 6) * 32 + c;
    const float scale = 0.0625f;
#pragma unroll
    for (int i = 0; i < 4; ++i) {
#pragma unroll
      for (int r = 0; r < 4; ++r) {
        const int orow = map_row(m0 + wm * 64 + i * 16 + 4 * g + r, cmap);
        const float2 sc0 = sct[orow * 128 + h0];
        const float2 sc1 = sct[orow * 128 + h0 + 16];
        US* qp = q_bf + ((size_t)orow * 8 + n) * 256 + base64 + c;
        const float q1 = acc[i][0][r], q2 = acc[i][1][r];
        const float q3 = acc[i][2][r], q4 = acc[i][3][r];
        qp[0]  = f2bf(scale * (q1 * sc0.y - q2 * sc0.x));
        qp[16] = f2bf(scale * (q2 * sc0.y + q1 * sc0.x));
        qp[32] = f2bf(scale * (q3 * sc1.y - q4 * sc1.x));
        qp[48] = f2bf(scale * (q4 * sc1.y + q3 * sc1.x));
      }
    }
  } else if (colb < 2304) {
    // k path: RoPE (no scale) -> k_bf physical (permuted, matches q) + k_out logical
    const int pcb = colb - 2048;           // {0,64,128,192}
    const int h0 = (pcb >> 6) * 32 + c;    // logical freq base
#pragma unroll
    for (int i = 0; i < 4; ++i) {
#pragma unroll
      for (int r = 0; r < 4; ++r) {
        const int orow = map_row(m0 + wm * 64 + i * 16 + 4 * g + r, cmap);
        const float2 sc0 = sct[orow * 128 + h0];
        const float2 sc1 = sct[orow * 128 + h0 + 16];
        const float q1 = acc[i][0][r], q2 = acc[i][1][r];
        const float q3 = acc[i][2][r], q4 = acc[i][3][r];
        const float o1 = q1 * sc0.y - q2 * sc0.x, o2 = q2 * sc0.y + q1 * sc0.x;
        const float o3 = q3 * sc1.y - q4 * sc1.x, o4 = q4 * sc1.y + q3 * sc1.x;
        US* kp = k_bf + (size_t)orow * 256 + pcb + c;
        kp[0] = f2bf(o1); kp[16] = f2bf(o2); kp[32] = f2bf(o3); kp[48] = f2bf(o4);
        float* ko = k_out + (size_t)orow * 256;
        ko[h0] = o1; ko[h0 + 128] = o2; ko[h0 + 16] = o3; ko[h0 + 144] = o4;
      }
    }
  } else {
    // v path: v_out fp32 (coalesced) + vt bf16 [b*256+h][t] (8B-packed along t)
    const int vcb = colb - 2304 + c;       // logical h base (+ j*16)
#pragma unroll
    for (int i = 0; i < 4; ++i) {
#pragma unroll
      for (int r = 0; r < 4; ++r) {
        const int orow = map_row(m0 + wm * 64 + i * 16 + 4 * g + r, cmap);
        float* vo = v_out + (size_t)orow * 256 + vcb;
#pragma unroll
        for (int j = 0; j < 4; ++j) vo[j * 16] = acc[i][j][r];
      }
      const int orow0 = map_row(m0 + wm * 64 + i * 16 + 4 * g, cmap);
      const int bb = orow0 >> 10, tt = orow0 & 1023;  // 4-aligned tt -> 8B-aligned store
#pragma unroll
      for (int j = 0; j < 4; ++j) {
        const int h = vcb + j * 16;
        u16x4 o;
        o[0] = f2bf(acc[i][j][0]); o[1] = f2bf(acc[i][j][1]);
        o[2] = f2bf(acc[i][j][2]); o[3] = f2bf(acc[i][j][3]);
        *reinterpret_cast<u16x4*>(vt + ((size_t)(bb * 256 + h)) * 1024 + tt) = o;
      }
    }
  }
}

// ------- compact output GEMM: 448 tiles (384 out0 + 64 out1), XCD-swizzled -------
__global__ __launch_bounds__(256, 2)
void k_gemm_out(const US* __restrict__ A, const US* __restrict__ BT0, const US* __restrict__ BT1,
                float* __restrict__ C0, float* __restrict__ C1) {
  const int bid = blockIdx.x;
  int id = (bid & 7) * 56 + (bid >> 3);   // bijective XCD swizzle (448 = 8*56)
  const US* BT; float* Cb; int amap, mt, ntile, Nst;
  if (id < 384) { amap = 1; mt = id / 16; ntile = id % 16; BT = BT0; Cb = C0; Nst = 2048; }
  else { id -= 384; amap = 2; mt = id / 8; ntile = id % 8; BT = BT1; Cb = C1; Nst = 1024; }
  const int m0 = mt * 128, n0 = ntile * 128;
  const int K = 2048;
  __shared__ __align__(16) US lA[2][128 * 32];
  __shared__ __align__(16) US lB[2][128 * 32];
  const int tid = threadIdx.x;
  const int lane = tid & 63;
  const int wid = tid >> 6;
  const int wm = wid >> 1, wn = wid & 1;
  const int g = lane >> 4, c = lane & 15;
  const int lrow = lane >> 2, lcol = (lane & 3) * 8;
  const size_t ga0 = (size_t)map_row(m0 + wid * 16 + lrow, amap) * K + lcol;
  const size_t ga1 = (size_t)map_row(m0 + 64 + wid * 16 + lrow, amap) * K + lcol;
  const size_t gb0 = (size_t)(n0 + wid * 16 + lrow) * K + lcol;
  const size_t gb1 = (size_t)(n0 + 64 + wid * 16 + lrow) * K + lcol;

  auto stage = [&](int bi, int k0) {
    gld16(A + ga0 + k0, &lA[bi][(wid * 16) * 32]);
    gld16(A + ga1 + k0, &lA[bi][(64 + wid * 16) * 32]);
    gld16(BT + gb0 + k0, &lB[bi][(wid * 16) * 32]);
    gld16(BT + gb1 + k0, &lB[bi][(64 + wid * 16) * 32]);
  };

  f32x4 acc[4][4];
#pragma unroll
  for (int i = 0; i < 4; ++i)
#pragma unroll
    for (int j = 0; j < 4; ++j) acc[i][j] = f32x4{0.f, 0.f, 0.f, 0.f};

  const int nt = K >> 5;
  stage(0, 0);
  __syncthreads();
  for (int t = 0; t < nt; ++t) {
    const int bi = t & 1;
    if (t + 1 < nt) stage(bi ^ 1, (t + 1) * 32);
    bf16x8 af[4], bfr[4];
#pragma unroll
    for (int i = 0; i < 4; ++i) {
      af[i] = *reinterpret_cast<const bf16x8*>(&lA[bi][(wm * 64 + i * 16 + c) * 32 + g * 8]);
      bfr[i] = *reinterpret_cast<const bf16x8*>(&lB[bi][(wn * 64 + i * 16 + c) * 32 + g * 8]);
    }
#pragma unroll
    for (int i = 0; i < 4; ++i)
#pragma unroll
      for (int j = 0; j < 4; ++j)
        acc[i][j] = mfma16(af[i], bfr[j], acc[i][j]);
    __syncthreads();
  }

  const int col = n0 + wn * 64 + c;
#pragma unroll
  for (int i = 0; i < 4; ++i) {
#pragma unroll
    for (int r = 0; r < 4; ++r) {
      const int orow = m0 + wm * 64 + i * 16 + 4 * g + r;  // compact per-segment row
      float* cp = Cb + (size_t)orow * Nst + col;
#pragma unroll
      for (int j = 0; j < 4; ++j) cp[j * 16] = acc[i][j][r];
    }
  }
}

// ------- flash attention (R8 structure) + overlapped wo weight-packing -------
__global__ __launch_bounds__(256, 2)
void k_attn(const US* __restrict__ qb, const US* __restrict__ kb,
            const US* __restrict__ vt, US* __restrict__ enc,
            const float* __restrict__ wo0, const float* __restrict__ wo1,
            US* __restrict__ bto0, US* __restrict__ bto1) {
  __shared__ __align__(16) US lK[2][32 * 256];   // 16KB x2
  __shared__ __align__(16) US lV[2][256 * 32];   // 16KB x2
  const int id = blockIdx.x;
  const int tid = threadIdx.x;

  if (id >= 512) {  // ---- wo pack path ----
    int local = id - 512;
    const float* src; US* dst; int C, CX;
    if (local < 4096) { src = wo0; dst = bto0; C = 2048; CX = 64; }
    else { local -= 4096; src = wo1; dst = bto1; C = 1024; CX = 32; }
    const int cx = local % CX, ry = local / CX;
    const int c0p = cx * 32, r0p = ry * 32;
    const int tx = tid & 31, ty = tid >> 5;
    float* tileF = (float*)&lK[0][0];  // 32x33 f32 aliases attn LDS
#pragma unroll
    for (int i = 0; i < 4; ++i)
      tileF[(ty + 8 * i) * 33 + tx] = src[(size_t)(r0p + ty + 8 * i) * C + c0p + tx];
    __syncthreads();
#pragma unroll
    for (int i = 0; i < 4; ++i)
      dst[(size_t)(c0p + ty + 8 * i) * 2048 + r0p + tx] = f2bf(tileF[tx * 33 + ty + 8 * i]);
    return;
  }

  // ---- attention path ----
  const int r0_ = (id < 256) ? id : 767 - id;    // work rank, descending length
  const int qt = 63 - (r0_ >> 3);
  const int hg = (r0_ >> 2) & 1;
  const int b = r0_ & 3;
  const int wid = tid >> 6;
  const int lane = tid & 63;
  const int g = lane >> 4, c = lane & 15;
  const int qbase = qt * 16;
  const int n = hg * 4 + wid;

  const US* kbB = kb + (size_t)b * 262144;
  const US* vtB = vt + (size_t)b * 262144;

  bf16x8 qf[8];
  {
    const US* qp = qb + ((size_t)((b * 1024 + qbase + c) * 8 + n)) * 256 + 8 * g;
#pragma unroll
    for (int ch = 0; ch < 8; ++ch)
      qf[ch] = *reinterpret_cast<const bf16x8*>(qp + ch * 32);
  }

  auto stage = [&](int bi, int c0) {
#pragma unroll
    for (int j = 0; j < 4; ++j) {
      const int rk = wid * 8 + j * 2 + (lane >> 5);
      const int sk = lane & 31;
      gld16(kbB + (size_t)(c0 + rk) * 256 + (sk ^ (rk & 7)) * 8,
            &lK[bi][(wid * 8 + j * 2) * 256]);
      const int rv = wid * 64 + j * 16 + (lane >> 2);
      const int sv = lane & 3;
      gld16(vtB + (size_t)rv * 1024 + c0 + (sv ^ ((rv >> 1) & 3)) * 8,
            &lV[bi][(wid * 64 + j * 16) * 32]);
    }
  };

  f32x4 acc[16];
#pragma unroll
  for (int i = 0; i < 16; ++i) acc[i] = f32x4{0.f, 0.f, 0.f, 0.f};
  float m_run = -3.0e38f, l_run = 0.f;

  const int nC = qbase / 32 + 1;
  stage(0, 0);
  __syncthreads();

  for (int i = 0; i < nC; ++i) {
    const int c0 = 32 * i;
    const int bi = i & 1;
    if (i + 1 < nC) stage(bi ^ 1, c0 + 32);

    const bool hb = (c0 + 16 <= qbase);
    f32x4 sA = {0.f, 0.f, 0.f, 0.f}, sB = {0.f, 0.f, 0.f, 0.f};
    __builtin_amdgcn_s_setprio(1);
#pragma unroll
    for (int ch = 0; ch < 8; ++ch) {
      const int slot = (((ch * 4 + g) ^ (c & 7)) * 8);
      sA = mfma16(*reinterpret_cast<const bf16x8*>(&lK[bi][c * 256 + slot]), qf[ch], sA);
    }
    if (hb) {
#pragma unroll
      for (int ch = 0; ch < 8; ++ch) {
        const int slot = (((ch * 4 + g) ^ (c & 7)) * 8);  // (c+16)&7 == c&7
        sB = mfma16(*reinterpret_cast<const bf16x8*>(&lK[bi][(c + 16) * 256 + slot]), qf[ch], sB);
      }
    }
    __builtin_amdgcn_s_setprio(0);
    if (c0 == qbase) {
#pragma unroll
      for (int r = 0; r < 4; ++r)
        if (4 * g + r > c) sA[r] = -3.0e38f;
    }
    if (hb && (c0 + 16 == qbase)) {
#pragma unroll
      for (int r = 0; r < 4; ++r)
        if (4 * g + r > c) sB[r] = -3.0e38f;
    }
    float tm = fmaxf(fmaxf(sA[0], sA[1]), fmaxf(sA[2], sA[3]));
    if (hb) tm = fmaxf(tm, fmaxf(fmaxf(sB[0], sB[1]), fmaxf(sB[2], sB[3])));
    tm = fmaxf(tm, __shfl_xor(tm, 16));
    tm = fmaxf(tm, __shfl_xor(tm, 32));
    // defer-max: only rescale when the running max actually grows past THR
    if (!__all(tm - m_run <= 8.0f)) {
      const float m_new = fmaxf(m_run, tm);
      const float alpha = __expf(m_run - m_new);
      float aacc[4];
#pragma unroll
      for (int r = 0; r < 4; ++r) aacc[r] = __shfl(alpha, 4 * g + r);
#pragma unroll
      for (int ht = 0; ht < 16; ++ht) {
        acc[ht][0] *= aacc[0]; acc[ht][1] *= aacc[1];
        acc[ht][2] *= aacc[2]; acc[ht][3] *= aacc[3];
      }
      l_run *= alpha;
      m_run = m_new;
    }
    float pA[4], pB[4];
    float ls = 0.f;
#pragma unroll
    for (int r = 0; r < 4; ++r) { pA[r] = __expf(sA[r] - m_run); ls += pA[r]; }
#pragma unroll
    for (int r = 0; r < 4; ++r) { pB[r] = hb ? __expf(sB[r] - m_run) : 0.f; ls += pB[r]; }
    ls += __shfl_xor(ls, 16);
    ls += __shfl_xor(ls, 32);
    l_run += ls;

    // --- paf butterfly: pack P to bf16 pairs, then 2-stage 4-lane-group transpose ---
    unsigned w0, w1, w2, w3;
    asm("v_cvt_pk_bf16_f32 %0, %1, %2" : "=v"(w0) : "v"(pA[0]), "v"(pA[1]));
    asm("v_cvt_pk_bf16_f32 %0, %1, %2" : "=v"(w1) : "v"(pA[2]), "v"(pA[3]));
    asm("v_cvt_pk_bf16_f32 %0, %1, %2" : "=v"(w2) : "v"(pB[0]), "v"(pB[1]));
    asm("v_cvt_pk_bf16_f32 %0, %1, %2" : "=v"(w3) : "v"(pB[2]), "v"(pB[3]));
    const bool bb1 = ((g >> 1) & 1) != 0, bb0 = (g & 1) != 0;
    unsigned ownA = bb1 ? w2 : w0, ownB = bb1 ? w3 : w1;
    unsigned sndA = bb1 ? w0 : w2, sndB = bb1 ? w1 : w3;
    unsigned rcvA = (unsigned)__shfl_xor((int)sndA, 32);
    unsigned rcvB = (unsigned)__shfl_xor((int)sndB, 32);
    unsigned kA = (bb0 == bb1) ? ownA : rcvA, kB = (bb0 == bb1) ? ownB : rcvB;
    unsigned s2A = (bb0 == bb1) ? rcvA : ownA, s2B = (bb0 == bb1) ? rcvB : ownB;
    unsigned gA = (unsigned)__shfl_xor((int)s2A, 16);
    unsigned gB = (unsigned)__shfl_xor((int)s2B, 16);
    union { unsigned u[4]; bf16x8 v; } pu;
    pu.u[0] = bb0 ? gA : kA; pu.u[1] = bb0 ? gB : kB;
    pu.u[2] = bb0 ? kA : gA; pu.u[3] = bb0 ? kB : gB;
    const bf16x8 paf = pu.v;

    __builtin_amdgcn_s_setprio(1);
#pragma unroll
    for (int ht = 0; ht < 16; ++ht) {
      const int h = ht * 16 + c;
      const int slot = (g ^ ((c >> 1) & 3)) * 8;
      bf16x8 vf = *reinterpret_cast<const bf16x8*>(&lV[bi][h * 32 + slot]);
      acc[ht] = mfma16(paf, vf, acc[ht]);
    }
    __builtin_amdgcn_s_setprio(0);
    __syncthreads();  // buf[bi] reads done; staging of buf[bi^1] drained
  }

  const float inv = 1.0f / l_run;
  float ia[4];
#pragma unroll
  for (int r = 0; r < 4; ++r) ia[r] = __shfl(inv, 4 * g + r);
#pragma unroll
  for (int ht = 0; ht < 16; ++ht) {
#pragma unroll
    for (int r = 0; r < 4; ++r) {
      size_t o = ((size_t)((b * 1024 + qbase + 4 * g + r) * 8 + n)) * 256 + ht * 16 + c;
      enc[o] = f2bf(acc[ht][r] * ia[r]);
    }
  }
}

extern "C" void kernel_launch(void* const* d_in, const int* in_sizes, int n_in,
                              void* d_out, int out_size, void* d_ws, size_t ws_size,
                              hipStream_t stream) {
  const float* x0 = (const float*)d_in[0];
  const float* x1 = (const float*)d_in[1];
  const float* wq0 = (const float*)d_in[2];
  const float* wkv0 = (const float*)d_in[3];
  const float* wo0 = (const float*)d_in[4];
  const float* wq1 = (const float*)d_in[5];
  const float* wkv1 = (const float*)d_in[6];
  const float* wo1 = (const float*)d_in[7];
  const int* pos = (const int*)d_in[8];
  float* out = (float*)d_out;

  float* out0 = out;                    // 4*768*2048
  float* out1 = out + 6291456;          // 4*256*1024
  float* k_out = out + 7340032;         // 4*1024*256
  float* v_out = out + 8388608;         // 4*1024*256

  char* ws = (char*)d_ws;
  size_t off = 0;
  auto alloc = [&](size_t bytes) {
    char* p = ws + off;
    off += (bytes + 255) & ~(size_t)255;
    return p;
  };
  US* x0b   = (US*)alloc(6291456ull * 2);
  US* x1b   = (US*)alloc(1048576ull * 2);
  US* btq0  = (US*)alloc(2048ull * 2048 * 2);   // btq0+btkv0 contiguous: [2560][2048]
  US* btkv0 = (US*)alloc(512ull * 2048 * 2);
  US* btq1  = (US*)alloc(2048ull * 1024 * 2);   // btq1+btkv1 contiguous: [2560][1024]
  US* btkv1 = (US*)alloc(512ull * 1024 * 2);
  US* bto0  = (US*)alloc(2048ull * 2048 * 2);
  US* bto1  = (US*)alloc(1024ull * 2048 * 2);
  US* q_bf = (US*)alloc(8388608ull * 2);
  US* k_bf = (US*)alloc(1048576ull * 2);
  US* vt   = (US*)alloc(1048576ull * 2 + 256);
  US* enc  = (US*)alloc(8388608ull * 2);
  float2* sct = (float2*)alloc(524288ull * 8);
  (void)btkv0; (void)btkv1;

  // phase 1: fused casts + qkv weight packs (q AND k permuted) + sin/cos table
  k_prep<<<16896, 256, 0, stream>>>(x0, x1, x0b, x1b, wq0, wkv0, wq1, wkv1,
                                    btq0, btkv0, btq1, btkv1, pos, sct);

  // phase 2: merged QKV GEMM with fully-fused epilogue (q/k rope, v transpose)
  k_gemm_qkv<<<640, 256, 0, stream>>>(x0b, x1b, btq0, btq1,
                                      q_bf, k_bf, k_out, v_out, vt, sct);

  // phase 3: causal flash attention + overlapped wo0/wo1 weight packs
  k_attn<<<6656, 256, 0, stream>>>(q_bf, k_bf, vt, enc, wo0, wo1, bto0, bto1);

  // phase 4: compact fused output GEMM (448 tiles, no holes)
  k_gemm_out<<<448, 256, 0, stream>>>(enc, bto0, bto1, out0, out1);
}